// Round 9
// baseline (124.893 us; speedup 1.0000x reference)
//
#include <hip/hip_runtime.h>
#include <math.h>

constexpr int B  = 2048;
constexpr int S  = 200;
constexpr int D  = 64;
constexpr int H  = 4;
constexpr int H1 = 64;
constexpr int H2 = 32;
constexpr int F  = 256;

constexpr int PW = 72;   // relay pitch (bf16)
constexpr int PD = 65;   // build-kernel LDS pitch (floats, conflict-free)

typedef short bf16x8 __attribute__((ext_vector_type(8)));
typedef float f32x4  __attribute__((ext_vector_type(4)));
typedef unsigned uint4v __attribute__((ext_vector_type(4)));

__device__ __forceinline__ unsigned cvtpk(float a, float b) {
    unsigned r;
    asm volatile("v_cvt_pk_bf16_f32 %0, %1, %2" : "=v"(r) : "v"(a), "v"(b));
    return r;
}

struct K4 { float4 a, b, c, d; };

// ---- workspace layout ----
constexpr size_t OUTH_OFF = 0;                         // B*H*D f32 = 2 MB
constexpr size_t QT_OFF   = 2u * 1024 * 1024;          // B*H*64 f32 = 2 MB
constexpr size_t W2I_OFF  = 4u * 1024 * 1024;          // 4 h * 4096 B = 16 KB
constexpr size_t WEFF_OFF = 4u * 1024 * 1024 + 65536;  // B*H*8192 B = 64 MB
constexpr size_t WS_NEED  = WEFF_OFF + (size_t)B * H * 8192;

// ---------------------------------------------------------------------------
// Build kernel: per (h, 16 b's) — stage W1[h] combos in LDS, emit per-(b,h)
// Weff fragment images (bf16, register-image order), qt[64] f32, and (once
// per h) the W2 fragment image.
//   Weff[d][k] = W1[h,d,k] + W1[h,192+d,k] + q_d * W1[h,128+d,k]
//   qt[k]      = b1[h,k] + sum_d q_d*(W1[h,64+d,k] - W1[h,192+d,k])
// Image: frag f = mt + 4*kk; lane l holds WeffT[16*mt+(l&15)][32*kk+(l>>4)*8 .. +8]
// at weff[(b*H+h)*4096 + f*512 + l*8]  (ushort units).
// ---------------------------------------------------------------------------
__global__ __launch_bounds__(256, 2) void build_kernel(
    const float* __restrict__ query, const float* __restrict__ W1,
    const float* __restrict__ b1, const float* __restrict__ W2,
    ushort* __restrict__ weff, float* __restrict__ qtg, ushort* __restrict__ w2i)
{
    __shared__ float SAD[64 * PD];   // [d][k] : A + D
    __shared__ float SC [64 * PD];   // [d][k] : C
    __shared__ float SBD[64 * PD];   // [d][k] : B - D
    __shared__ float sQp[2][4][64];

    const int t  = threadIdx.x;
    const int h  = blockIdx.x & 3;
    const int bc = blockIdx.x >> 2;          // 0..127
    const float* w1h = W1 + (size_t)h * F * H1;

    // ---- W2 fragment image, once per h ----
    if (bc == 0) {
        const float* w2h = W2 + (size_t)h * H1 * H2;   // [k2][m]
        const int l = t & 63, f2 = t >> 6;
        const int mt2 = f2 & 1, w = f2 >> 1;
        const int m = 16 * mt2 + (l & 15), k20 = 32 * w + ((l >> 4) << 3);
        unsigned p0 = cvtpk(w2h[(k20 + 0) * 32 + m], w2h[(k20 + 1) * 32 + m]);
        unsigned p1 = cvtpk(w2h[(k20 + 2) * 32 + m], w2h[(k20 + 3) * 32 + m]);
        unsigned p2 = cvtpk(w2h[(k20 + 4) * 32 + m], w2h[(k20 + 5) * 32 + m]);
        unsigned p3 = cvtpk(w2h[(k20 + 6) * 32 + m], w2h[(k20 + 7) * 32 + m]);
        uint4v v = { p0, p1, p2, p3 };
        *(uint4v*)&w2i[(size_t)h * 2048 + f2 * 512 + l * 8] = v;
    }

    // ---- stage combos [d][k], coalesced reads, conflict-free writes ----
    {
        const int k = t & 63, dq = t >> 6;
        #pragma unroll
        for (int it = 0; it < 16; ++it) {
            const int d = it * 4 + dq;
            float a  = w1h[d * 64 + k];
            float bb = w1h[(64 + d) * 64 + k];
            float c  = w1h[(128 + d) * 64 + k];
            float dd = w1h[(192 + d) * 64 + k];
            SAD[d * PD + k] = a + dd;
            SC [d * PD + k] = c;
            SBD[d * PD + k] = bb - dd;
        }
    }
    __syncthreads();

    const int l  = t & 63;
    const int fh = t >> 6;      // mt = fh for both frags of this thread

    for (int bi = 0; bi < 16; ++bi) {
        const int b = bc * 16 + bi;
        const float* qb = query + (size_t)b * D;
        ushort* wout = weff + (size_t)(b * H + h) * 4096;

        // ---- two Weff fragments: f = fh (kk=0) and fh+4 (kk=1) ----
        #pragma unroll
        for (int ff = 0; ff < 2; ++ff) {
            const int f  = fh + 4 * ff;
            const int k  = 16 * fh + (l & 15);
            const int d0 = 32 * ff + ((l >> 4) << 3);
            f32x4 q0 = *(const f32x4*)&qb[d0];
            f32x4 q1 = *(const f32x4*)&qb[d0 + 4];
            float w[8];
            #pragma unroll
            for (int j = 0; j < 4; ++j)
                w[j] = SAD[(d0 + j) * PD + k] + q0[j] * SC[(d0 + j) * PD + k];
            #pragma unroll
            for (int j = 0; j < 4; ++j)
                w[4 + j] = SAD[(d0 + 4 + j) * PD + k] + q1[j] * SC[(d0 + 4 + j) * PD + k];
            uint4v v = { cvtpk(w[0], w[1]), cvtpk(w[2], w[3]),
                         cvtpk(w[4], w[5]), cvtpk(w[6], w[7]) };
            *(uint4v*)&wout[f * 512 + l * 8] = v;
        }

        // ---- qt partials ----
        {
            const int k = t & 63, part = t >> 6;
            float s = 0.f;
            #pragma unroll
            for (int j = 0; j < 16; ++j) {
                const int d = part * 16 + j;
                s += qb[d] * SBD[d * PD + k];
            }
            sQp[bi & 1][part][k] = s;
        }
        __syncthreads();
        if (t < 64)
            qtg[(size_t)(b * H + h) * 64 + t] = b1[h * 64 + t]
                + sQp[bi & 1][0][t] + sQp[bi & 1][1][t]
                + sQp[bi & 1][2][t] + sQp[bi & 1][3][t];
        // next iteration writes the other sQp buffer; its barrier orders reuse
    }
}

// ---------------------------------------------------------------------------
// Lean score+attend: one block per (b,h), 4 waves, ~11 KB LDS, prologue =
// pure coalesced fragment loads (no LDS staging, no barriers before loop).
// ---------------------------------------------------------------------------
__global__ __launch_bounds__(256, 2) void score_attend_kernel(
    const float* __restrict__ keys, const int* __restrict__ mask,
    const ushort* __restrict__ weff, const float* __restrict__ qtg,
    const ushort* __restrict__ w2i,
    const float* __restrict__ b2, const float* __restrict__ W3,
    const float* __restrict__ b3, const float* __restrict__ a1,
    const float* __restrict__ a2,
    float* __restrict__ outh)
{
    __shared__ ushort H1r[4][16 * PW];   // per-wave h1 relay
    __shared__ float sSc[208];
    __shared__ float sQp[4][64];

    // XCD-bijective swizzle: 4 h-blocks of each b adjacent in time on one XCD.
    const int wg   = blockIdx.x;
    const int rank = (wg & 7) * 1024 + (wg >> 3);
    const int b = rank >> 2;
    const int h = rank & 3;

    const int t    = threadIdx.x;
    const int lane = t & 63;
    const int wave = t >> 6;
    const int g    = lane >> 4;
    const int ln16 = lane & 15;

    auto loadKeys = [&](int st) -> K4 {
        int s = st * 16 + ln16;
        if (s > 199) s = 199;
        const float* krow = keys + ((size_t)b * S + s) * D;
        K4 r;
        r.a = *(const float4*)&krow[g * 8];
        r.b = *(const float4*)&krow[g * 8 + 4];
        r.c = *(const float4*)&krow[32 + g * 8];
        r.d = *(const float4*)&krow[32 + g * 8 + 4];
        return r;
    };

    // ---- issue first keys tile immediately ----
    K4 cur = loadKeys(wave);

    // ---- mask prefetch (softmax wave) ----
    int mval[4] = {0, 0, 0, 0};
    if (wave == 3) {
        #pragma unroll
        for (int c = 0; c < 4; ++c) {
            int s = lane + 64 * c;
            mval[c] = (s < S) ? mask[(size_t)b * S + s] : 0;
        }
    }

    // ---- fragment loads (register images, 16 B/lane coalesced) ----
    const ushort* wimg = weff + (size_t)(b * H + h) * 4096;
    bf16x8 wh[4][2];
    #pragma unroll
    for (int mt = 0; mt < 4; ++mt)
        #pragma unroll
        for (int kk = 0; kk < 2; ++kk)
            wh[mt][kk] = *(const bf16x8*)&wimg[(kk * 4 + mt) * 512 + lane * 8];

    const ushort* w2img = w2i + (size_t)h * 2048;
    bf16x8 w2f[2][2];
    #pragma unroll
    for (int w = 0; w < 2; ++w)
        #pragma unroll
        for (int mt2 = 0; mt2 < 2; ++mt2)
            w2f[w][mt2] = *(const bf16x8*)&w2img[(w * 2 + mt2) * 512 + lane * 8];

    const float* qtb = qtg + (size_t)(b * H + h) * 64;
    f32x4 qtv[4];
    #pragma unroll
    for (int mt = 0; mt < 4; ++mt) qtv[mt] = *(const f32x4*)&qtb[mt * 16 + g * 4];

    f32x4 b2v[2], w3v[2];
    #pragma unroll
    for (int mt2 = 0; mt2 < 2; ++mt2) {
        b2v[mt2] = *(const f32x4*)&b2[h * 32 + mt2 * 16 + g * 4];
        w3v[mt2] = *(const f32x4*)&W3[h * 32 + mt2 * 16 + g * 4];
    }
    const float a1v = a1[h], a2v = a2[h], b3v = b3[h];
    ushort* myH1 = H1r[wave];

    auto computeTile = [&](const K4& kf, int st) {
        uint4v u0 = { cvtpk(kf.a.x, kf.a.y), cvtpk(kf.a.z, kf.a.w),
                      cvtpk(kf.b.x, kf.b.y), cvtpk(kf.b.z, kf.b.w) };
        uint4v u1 = { cvtpk(kf.c.x, kf.c.y), cvtpk(kf.c.z, kf.c.w),
                      cvtpk(kf.d.x, kf.d.y), cvtpk(kf.d.z, kf.d.w) };
        bf16x8 bk0 = __builtin_bit_cast(bf16x8, u0);
        bf16x8 bk1 = __builtin_bit_cast(bf16x8, u1);

        // layer 1 (transposed): acc[mt] = h1T[k=16mt+4g+i][s=ln16], qt as C-init
        f32x4 acc[4] = { qtv[0], qtv[1], qtv[2], qtv[3] };
        #pragma unroll
        for (int mt = 0; mt < 4; ++mt)
            acc[mt] = __builtin_amdgcn_mfma_f32_16x16x32_bf16(wh[mt][0], bk0, acc[mt], 0, 0, 0);
        #pragma unroll
        for (int mt = 0; mt < 4; ++mt)
            acc[mt] = __builtin_amdgcn_mfma_f32_16x16x32_bf16(wh[mt][1], bk1, acc[mt], 0, 0, 0);

        // epilogue: prelu, bf16 hi, relay via wave-private LDS [s][k]
        #pragma unroll
        for (int mt = 0; mt < 4; ++mt) {
            float v0 = acc[mt][0]; v0 = v0 > 0.f ? v0 : a1v * v0;
            float v1 = acc[mt][1]; v1 = v1 > 0.f ? v1 : a1v * v1;
            float v2 = acc[mt][2]; v2 = v2 > 0.f ? v2 : a1v * v2;
            float v3 = acc[mt][3]; v3 = v3 > 0.f ? v3 : a1v * v3;
            *(uint2*)&myH1[ln16 * PW + mt * 16 + g * 4] =
                make_uint2(cvtpk(v0, v1), cvtpk(v2, v3));
        }

        // layer 2: D2[m][s] = W2T @ h1T, b2 as C-init
        f32x4 acc2[2] = { b2v[0], b2v[1] };
        #pragma unroll
        for (int w = 0; w < 2; ++w) {
            bf16x8 Bh = *(const bf16x8*)&myH1[ln16 * PW + w * 32 + g * 8];
            #pragma unroll
            for (int mt2 = 0; mt2 < 2; ++mt2)
                acc2[mt2] = __builtin_amdgcn_mfma_f32_16x16x32_bf16(w2f[w][mt2], Bh, acc2[mt2], 0, 0, 0);
        }

        // layer 3: prelu + dot W3, reduce over lane-groups, score -> LDS
        float part = 0.f;
        #pragma unroll
        for (int mt2 = 0; mt2 < 2; ++mt2) {
            #pragma unroll
            for (int i = 0; i < 4; ++i) {
                float v = acc2[mt2][i];
                v = v > 0.f ? v : a2v * v;
                part += v * w3v[mt2][i];
            }
        }
        part += __shfl_xor(part, 16);
        part += __shfl_xor(part, 32);
        const int s = st * 16 + ln16;
        if (lane < 16 && s < 200) sSc[s] = part + b3v;
    };

    // ---- main loop: barrier-free, software-pipelined keys ----
    #pragma unroll
    for (int it = 0; it < 4; ++it) {
        const int st  = wave + 4 * it;
        const int stn = st + 4;
        K4 nxt = cur;
        if (stn < 13) nxt = loadKeys(stn);
        if (st  < 13) computeTile(cur, st);
        cur = nxt;
    }
    __syncthreads();

    // ---- masked softmax over 200 scores (wave 3 holds prefetched mask) ----
    if (wave == 3) {
        float v[4];
        float M = -INFINITY;
        #pragma unroll
        for (int c = 0; c < 4; ++c) {
            int s = lane + 64 * c;
            v[c] = (s < S && mval[c]) ? sSc[s] : -INFINITY;
            M = fmaxf(M, v[c]);
        }
        #pragma unroll
        for (int off = 32; off > 0; off >>= 1) M = fmaxf(M, __shfl_xor(M, off));
        float Z = 0.f, e[4];
        #pragma unroll
        for (int c = 0; c < 4; ++c) { e[c] = mval[c] ? __expf(v[c] - M) : 0.f; Z += e[c]; }
        #pragma unroll
        for (int off = 32; off > 0; off >>= 1) Z += __shfl_xor(Z, off);
        const float inv = Z > 0.f ? 1.f / Z : 0.f;
        #pragma unroll
        for (int c = 0; c < 4; ++c) { int s = lane + 64 * c; if (s < S) sSc[s] = e[c] * inv; }
    }
    __syncthreads();

    // ---- weighted key sum (keys re-read, L2/L3-hot) ----
    {
        const int d = lane;
        float acc = 0.f;
        #pragma unroll 5
        for (int i = 0; i < 50; ++i) {
            int s = wave * 50 + i;
            acc += sSc[s] * keys[((size_t)b * S + s) * D + d];
        }
        sQp[wave][d] = acc;
    }
    __syncthreads();
    if (t < 64)
        outh[((size_t)b * H + h) * D + t] = sQp[0][t] + sQp[1][t] + sQp[2][t] + sQp[3][t];
}

// ---------------------------------------------------------------------------
// Fallback (round-8 path) if the workspace is too small for the images.
// ---------------------------------------------------------------------------
__global__ __launch_bounds__(256, 2) void score_attend_fb(
    const float* __restrict__ query, const float* __restrict__ keys,
    const int* __restrict__ mask,
    const float* __restrict__ W1, const float* __restrict__ b1, const float* __restrict__ a1,
    const float* __restrict__ W2, const float* __restrict__ b2, const float* __restrict__ a2,
    const float* __restrict__ W3, const float* __restrict__ b3,
    float* __restrict__ outh)
{
    __shared__ union UW {
        ushort WTh[H1 * PW];
        ushort H1r[4][16 * PW];
    } uu;
    __shared__ ushort sW2h[H2 * PW];
    __shared__ float sQ[64], sQt[64], sQp[4][64];
    __shared__ float sB2[32], sW3v[32];
    __shared__ float sSc[208];

    const int wg   = blockIdx.x;
    const int rank = (wg & 7) * 1024 + (wg >> 3);
    const int b = rank >> 2;
    const int h = rank & 3;

    const int t    = threadIdx.x;
    const int lane = t & 63;
    const int wave = t >> 6;
    const int g    = lane >> 4;
    const int ln16 = lane & 15;

    const float* w1h = W1 + (size_t)h * F * H1;

    auto loadKeys = [&](int st) -> K4 {
        int s = st * 16 + ln16;
        if (s > 199) s = 199;
        const float* krow = keys + ((size_t)b * S + s) * D;
        K4 r;
        r.a = *(const float4*)&krow[g * 8];
        r.b = *(const float4*)&krow[g * 8 + 4];
        r.c = *(const float4*)&krow[32 + g * 8];
        r.d = *(const float4*)&krow[32 + g * 8 + 4];
        return r;
    };
    K4 cur = loadKeys(wave);

    int mval[4] = {0, 0, 0, 0};
    if (wave == 3) {
        #pragma unroll
        for (int c = 0; c < 4; ++c) {
            int s = lane + 64 * c;
            mval[c] = (s < S) ? mask[(size_t)b * S + s] : 0;
        }
    }

    if (t < 64) sQ[t] = query[(size_t)b * D + t];
    if (t < 32) { sB2[t] = b2[h * 32 + t]; sW3v[t] = W3[h * 32 + t]; }
    {
        const float* w2h = W2 + (size_t)h * H1 * H2;
        const int m = t & 31, kg = t >> 5;
        unsigned pk0 = cvtpk(w2h[(kg * 8 + 0) * 32 + m], w2h[(kg * 8 + 1) * 32 + m]);
        unsigned pk1 = cvtpk(w2h[(kg * 8 + 2) * 32 + m], w2h[(kg * 8 + 3) * 32 + m]);
        unsigned pk2 = cvtpk(w2h[(kg * 8 + 4) * 32 + m], w2h[(kg * 8 + 5) * 32 + m]);
        unsigned pk3 = cvtpk(w2h[(kg * 8 + 6) * 32 + m], w2h[(kg * 8 + 7) * 32 + m]);
        uint4v v = { pk0, pk1, pk2, pk3 };
        *(uint4v*)&sW2h[m * PW + kg * 8] = v;
    }
    __syncthreads();

    {
        const int k = t & 63, dg = t >> 6;
        float qtp = 0.f;
        unsigned hw[8];
        #pragma unroll
        for (int j2 = 0; j2 < 8; ++j2) {
            const int d0 = dg * 16 + 2 * j2, d1 = d0 + 1;
            float A0 = w1h[d0 * 64 + k], B0 = w1h[(64 + d0) * 64 + k];
            float C0 = w1h[(128 + d0) * 64 + k], D0 = w1h[(192 + d0) * 64 + k];
            float A1 = w1h[d1 * 64 + k], B1 = w1h[(64 + d1) * 64 + k];
            float C1 = w1h[(128 + d1) * 64 + k], D1 = w1h[(192 + d1) * 64 + k];
            float w0 = A0 + D0 + sQ[d0] * C0;
            float w1 = A1 + D1 + sQ[d1] * C1;
            qtp += sQ[d0] * (B0 - D0) + sQ[d1] * (B1 - D1);
            hw[j2] = cvtpk(w0, w1);
        }
        uint4v hv0 = { hw[0], hw[1], hw[2], hw[3] };
        uint4v hv1 = { hw[4], hw[5], hw[6], hw[7] };
        *(uint4v*)&uu.WTh[k * PW + dg * 16]     = hv0;
        *(uint4v*)&uu.WTh[k * PW + dg * 16 + 8] = hv1;
        sQp[dg][k] = qtp;
    }
    __syncthreads();

    bf16x8 wh[4][2];
    #pragma unroll
    for (int mt = 0; mt < 4; ++mt)
        #pragma unroll
        for (int kk = 0; kk < 2; ++kk)
            wh[mt][kk] = *(const bf16x8*)&uu.WTh[(mt * 16 + ln16) * PW + kk * 32 + g * 8];
    if (t < 64) sQt[t] = b1[h * 64 + t] + sQp[0][t] + sQp[1][t] + sQp[2][t] + sQp[3][t];
    __syncthreads();

    f32x4 qtv[4];
    #pragma unroll
    for (int mt = 0; mt < 4; ++mt) qtv[mt] = *(const f32x4*)&sQt[mt * 16 + g * 4];
    f32x4 b2v[2], w3v[2];
    #pragma unroll
    for (int mt2 = 0; mt2 < 2; ++mt2) {
        b2v[mt2] = *(const f32x4*)&sB2[mt2 * 16 + g * 4];
        w3v[mt2] = *(const f32x4*)&sW3v[mt2 * 16 + g * 4];
    }
    const float a1v = a1[h], a2v = a2[h], b3v = b3[h];
    ushort* myH1 = uu.H1r[wave];

    auto computeTile = [&](const K4& kf, int st) {
        uint4v u0 = { cvtpk(kf.a.x, kf.a.y), cvtpk(kf.a.z, kf.a.w),
                      cvtpk(kf.b.x, kf.b.y), cvtpk(kf.b.z, kf.b.w) };
        uint4v u1 = { cvtpk(kf.c.x, kf.c.y), cvtpk(kf.c.z, kf.c.w),
                      cvtpk(kf.d.x, kf.d.y), cvtpk(kf.d.z, kf.d.w) };
        bf16x8 bk0 = __builtin_bit_cast(bf16x8, u0);
        bf16x8 bk1 = __builtin_bit_cast(bf16x8, u1);
        f32x4 acc[4] = { qtv[0], qtv[1], qtv[2], qtv[3] };
        #pragma unroll
        for (int mt = 0; mt < 4; ++mt)
            acc[mt] = __builtin_amdgcn_mfma_f32_16x16x32_bf16(wh[mt][0], bk0, acc[mt], 0, 0, 0);
        #pragma unroll
        for (int mt = 0; mt < 4; ++mt)
            acc[mt] = __builtin_amdgcn_mfma_f32_16x16x32_bf16(wh[mt][1], bk1, acc[mt], 0, 0, 0);
        #pragma unroll
        for (int mt = 0; mt < 4; ++mt) {
            float v0 = acc[mt][0]; v0 = v0 > 0.f ? v0 : a1v * v0;
            float v1 = acc[mt][1]; v1 = v1 > 0.f ? v1 : a1v * v1;
            float v2 = acc[mt][2]; v2 = v2 > 0.f ? v2 : a1v * v2;
            float v3 = acc[mt][3]; v3 = v3 > 0.f ? v3 : a1v * v3;
            *(uint2*)&myH1[ln16 * PW + mt * 16 + g * 4] =
                make_uint2(cvtpk(v0, v1), cvtpk(v2, v3));
        }
        f32x4 acc2[2] = { b2v[0], b2v[1] };
        #pragma unroll
        for (int w = 0; w < 2; ++w) {
            bf16x8 Bh = *(const bf16x8*)&myH1[ln16 * PW + w * 32 + g * 8];
            #pragma unroll
            for (int mt2 = 0; mt2 < 2; ++mt2) {
                bf16x8 ah = *(const bf16x8*)&sW2h[(mt2 * 16 + ln16) * PW + w * 32 + g * 8];
                acc2[mt2] = __builtin_amdgcn_mfma_f32_16x16x32_bf16(ah, Bh, acc2[mt2], 0, 0, 0);
            }
        }
        float part = 0.f;
        #pragma unroll
        for (int mt2 = 0; mt2 < 2; ++mt2) {
            #pragma unroll
            for (int i = 0; i < 4; ++i) {
                float v = acc2[mt2][i];
                v = v > 0.f ? v : a2v * v;
                part += v * w3v[mt2][i];
            }
        }
        part += __shfl_xor(part, 16);
        part += __shfl_xor(part, 32);
        const int s = st * 16 + ln16;
        if (lane < 16 && s < 200) sSc[s] = part + b3v;
    };

    #pragma unroll
    for (int it = 0; it < 4; ++it) {
        const int st  = wave + 4 * it;
        const int stn = st + 4;
        K4 nxt = cur;
        if (stn < 13) nxt = loadKeys(stn);
        if (st  < 13) computeTile(cur, st);
        cur = nxt;
    }
    __syncthreads();

    if (wave == 3) {
        float v[4];
        float M = -INFINITY;
        #pragma unroll
        for (int c = 0; c < 4; ++c) {
            int s = lane + 64 * c;
            v[c] = (s < S && mval[c]) ? sSc[s] : -INFINITY;
            M = fmaxf(M, v[c]);
        }
        #pragma unroll
        for (int off = 32; off > 0; off >>= 1) M = fmaxf(M, __shfl_xor(M, off));
        float Z = 0.f, e[4];
        #pragma unroll
        for (int c = 0; c < 4; ++c) { e[c] = mval[c] ? __expf(v[c] - M) : 0.f; Z += e[c]; }
        #pragma unroll
        for (int off = 32; off > 0; off >>= 1) Z += __shfl_xor(Z, off);
        const float inv = Z > 0.f ? 1.f / Z : 0.f;
        #pragma unroll
        for (int c = 0; c < 4; ++c) { int s = lane + 64 * c; if (s < S) sSc[s] = e[c] * inv; }
    }
    __syncthreads();

    {
        const int d = lane;
        float acc = 0.f;
        #pragma unroll 5
        for (int i = 0; i < 50; ++i) {
            int s = wave * 50 + i;
            acc += sSc[s] * keys[((size_t)b * S + s) * D + d];
        }
        sQp[wave][d] = acc;
    }
    __syncthreads();
    if (t < 64)
        outh[((size_t)b * H + h) * D + t] = sQp[0][t] + sQp[1][t] + sQp[2][t] + sQp[3][t];
}

// ---------------------------------------------------------------------------
// Projection: out[b] = (mean_h outh[b,h,:]) @ Wo + bo.  4 b-rows per block.
// ---------------------------------------------------------------------------
__global__ __launch_bounds__(256) void proj_kernel(
    const float* __restrict__ outh, const float* __restrict__ Wo,
    const float* __restrict__ bo, float* __restrict__ out)
{
    __shared__ float comb[4][64];
    const int t = threadIdx.x, bb = t >> 6, j = t & 63;
    const size_t b = (size_t)blockIdx.x * 4 + bb;

    const float* oh = outh + b * H * D;
    comb[bb][j] = 0.25f * (oh[j] + oh[64 + j] + oh[128 + j] + oh[192 + j]);
    __syncthreads();

    float o = bo[j];
    #pragma unroll 8
    for (int d = 0; d < 64; ++d)
        o += comb[bb][d] * Wo[d * 64 + j];
    out[b * D + j] = o;
}

// ---------------------------------------------------------------------------
extern "C" void kernel_launch(void* const* d_in, const int* in_sizes, int n_in,
                              void* d_out, int out_size, void* d_ws, size_t ws_size,
                              hipStream_t stream) {
    const float* query = (const float*)d_in[0];
    const float* keys  = (const float*)d_in[1];
    const int*   mask  = (const int*)d_in[2];
    const float* W1 = (const float*)d_in[3];
    const float* b1 = (const float*)d_in[4];
    const float* a1 = (const float*)d_in[5];
    const float* W2 = (const float*)d_in[6];
    const float* b2 = (const float*)d_in[7];
    const float* a2 = (const float*)d_in[8];
    const float* W3 = (const float*)d_in[9];
    const float* b3 = (const float*)d_in[10];
    const float* Wo = (const float*)d_in[11];
    const float* bo = (const float*)d_in[12];

    float* out  = (float*)d_out;
    char*  ws   = (char*)d_ws;
    float* outh = (float*)(ws + OUTH_OFF);

    if (ws_size >= WS_NEED) {
        float*  qtg  = (float*)(ws + QT_OFF);
        ushort* w2i  = (ushort*)(ws + W2I_OFF);
        ushort* weff = (ushort*)(ws + WEFF_OFF);
        build_kernel<<<dim3(H * (B / 16)), 256, 0, stream>>>(
            query, W1, b1, W2, weff, qtg, w2i);
        score_attend_kernel<<<dim3(B * H), 256, 0, stream>>>(
            keys, mask, weff, qtg, w2i, b2, W3, b3, a1, a2, outh);
    } else {
        score_attend_fb<<<dim3(B * H), 256, 0, stream>>>(
            query, keys, mask, W1, b1, a1, W2, b2, a2, W3, b3, outh);
    }
    proj_kernel<<<dim3(B / 4), 256, 0, stream>>>(outh, Wo, bo, out);
}

// Round 10
// 109.102 us; speedup vs baseline: 1.1447x; 1.1447x over previous
//
#include <hip/hip_runtime.h>
#include <math.h>

constexpr int B  = 2048;
constexpr int S  = 200;
constexpr int D  = 64;
constexpr int H  = 4;
constexpr int H1 = 64;
constexpr int H2 = 32;
constexpr int F  = 256;

constexpr int PW = 72;   // bf16 LDS pitch (144 B rows; frag patterns ~2-way banks)

typedef short bf16x8 __attribute__((ext_vector_type(8)));
typedef float f32x4  __attribute__((ext_vector_type(4)));
typedef unsigned uint4v __attribute__((ext_vector_type(4)));

__device__ __forceinline__ unsigned cvtpk(float a, float b) {
    unsigned r;
    asm volatile("v_cvt_pk_bf16_f32 %0, %1, %2" : "=v"(r) : "v"(a), "v"(b));
    return r;
}

struct K4 { float4 a, b, c, d; };

// ---------------------------------------------------------------------------
// Fused score+attend: one block per (b,h), 4 waves, ~25 KB LDS.
//   Weff[d][k] = W1[h,d,k] + W1[h,192+d,k] + q_d * W1[h,128+d,k]   (hi bf16)
//   qt[k]      = b1[h,k] + sum_d q_d*(W1[h,64+d,k] - W1[h,192+d,k])
//   layer1 transposed (h1T = WeffT @ keysT, qt as C-init), 2-stage software
//   pipeline over s-tiles with double relay buffers (layer1 of tile t+1
//   overlaps the LDS relay round-trip of tile t), layer2 (b2 as C-init),
//   layer3 -> scores -> softmax -> vectorized weighted key sum -> outh.
// ---------------------------------------------------------------------------
__global__ __launch_bounds__(256, 2) void score_attend_kernel(
    const float* __restrict__ query, const float* __restrict__ keys,
    const int* __restrict__ mask,
    const float* __restrict__ W1, const float* __restrict__ b1, const float* __restrict__ a1,
    const float* __restrict__ W2, const float* __restrict__ b2, const float* __restrict__ a2,
    const float* __restrict__ W3, const float* __restrict__ b3,
    float* __restrict__ outh)
{
    __shared__ union UW {
        ushort WTh[H1 * PW];        // WeffT [k][d] hi  (build-then-dead)
        ushort H1r[8][16 * PW];     // 2 relay buffers per wave
    } uu;
    __shared__ ushort sW2h[H2 * PW];
    __shared__ float sQ[64], sQt[64], sQp[4][64];
    __shared__ float sSc[208];

    // XCD-bijective swizzle: 4 h-blocks of each b adjacent in time on one XCD.
    const int wg   = blockIdx.x;
    const int rank = (wg & 7) * 1024 + (wg >> 3);
    const int b = rank >> 2;
    const int h = rank & 3;

    const int t    = threadIdx.x;
    const int lane = t & 63;
    const int wave = t >> 6;
    const int g    = lane >> 4;
    const int ln16 = lane & 15;

    const float* w1h = W1 + (size_t)h * F * H1;

    auto loadKeys = [&](int st) -> K4 {
        int s = st * 16 + ln16;
        if (s > 199) s = 199;
        const float* krow = keys + ((size_t)b * S + s) * D;
        K4 r;
        r.a = *(const float4*)&krow[g * 8];
        r.b = *(const float4*)&krow[g * 8 + 4];
        r.c = *(const float4*)&krow[32 + g * 8];
        r.d = *(const float4*)&krow[32 + g * 8 + 4];
        return r;
    };

    // ---- issue first keys tile immediately (hidden under prologue) ----
    K4 k0 = loadKeys(wave);

    // ---- mask prefetch (softmax wave) ----
    int mval[4] = {0, 0, 0, 0};
    if (wave == 3) {
        #pragma unroll
        for (int c = 0; c < 4; ++c) {
            int s = lane + 64 * c;
            mval[c] = (s < S) ? mask[(size_t)b * S + s] : 0;
        }
    }

    // ---- P0: stage q, W2T hi (vectorized b128 write) ----
    if (t < 64) sQ[t] = query[(size_t)b * D + t];
    {
        const float* w2h = W2 + (size_t)h * H1 * H2;   // [k2][m]
        const int m = t & 31, kg = t >> 5;             // thread owns 8 k2 for one m
        unsigned pk0 = cvtpk(w2h[(kg * 8 + 0) * 32 + m], w2h[(kg * 8 + 1) * 32 + m]);
        unsigned pk1 = cvtpk(w2h[(kg * 8 + 2) * 32 + m], w2h[(kg * 8 + 3) * 32 + m]);
        unsigned pk2 = cvtpk(w2h[(kg * 8 + 4) * 32 + m], w2h[(kg * 8 + 5) * 32 + m]);
        unsigned pk3 = cvtpk(w2h[(kg * 8 + 6) * 32 + m], w2h[(kg * 8 + 7) * 32 + m]);
        uint4v v = { pk0, pk1, pk2, pk3 };
        *(uint4v*)&sW2h[m * PW + kg * 8] = v;
    }
    __syncthreads();

    // ---- hoist W2 fragments to registers (sW2h ready) ----
    bf16x8 w2f[2][2];
    #pragma unroll
    for (int w = 0; w < 2; ++w)
        #pragma unroll
        for (int mt2 = 0; mt2 < 2; ++mt2)
            w2f[w][mt2] = *(const bf16x8*)&sW2h[(mt2 * 16 + ln16) * PW + w * 32 + g * 8];

    // ---- P1: build WeffT hi (b128 writes) + qt partials ----
    {
        const int k = t & 63, dg = t >> 6;
        float qtp = 0.f;
        unsigned hw[8];
        #pragma unroll
        for (int j2 = 0; j2 < 8; ++j2) {
            const int d0 = dg * 16 + 2 * j2, d1 = d0 + 1;
            float A0 = w1h[d0 * 64 + k], B0 = w1h[(64 + d0) * 64 + k];
            float C0 = w1h[(128 + d0) * 64 + k], D0 = w1h[(192 + d0) * 64 + k];
            float A1 = w1h[d1 * 64 + k], B1 = w1h[(64 + d1) * 64 + k];
            float C1 = w1h[(128 + d1) * 64 + k], D1 = w1h[(192 + d1) * 64 + k];
            float w0 = A0 + D0 + sQ[d0] * C0;
            float w1 = A1 + D1 + sQ[d1] * C1;
            qtp += sQ[d0] * (B0 - D0) + sQ[d1] * (B1 - D1);
            hw[j2] = cvtpk(w0, w1);
        }
        uint4v hv0 = { hw[0], hw[1], hw[2], hw[3] };
        uint4v hv1 = { hw[4], hw[5], hw[6], hw[7] };
        *(uint4v*)&uu.WTh[k * PW + dg * 16]     = hv0;
        *(uint4v*)&uu.WTh[k * PW + dg * 16 + 8] = hv1;
        sQp[dg][k] = qtp;
    }
    __syncthreads();

    // ---- hoist WeffT fragments; finalize qt ----
    bf16x8 wh[4][2];
    #pragma unroll
    for (int mt = 0; mt < 4; ++mt)
        #pragma unroll
        for (int kk = 0; kk < 2; ++kk)
            wh[mt][kk] = *(const bf16x8*)&uu.WTh[(mt * 16 + ln16) * PW + kk * 32 + g * 8];
    if (t < 64) sQt[t] = b1[h * 64 + t] + sQp[0][t] + sQp[1][t] + sQp[2][t] + sQp[3][t];
    __syncthreads();   // all waves done reading WTh -> relay buffers may overlay

    f32x4 qtv[4];
    #pragma unroll
    for (int mt = 0; mt < 4; ++mt) qtv[mt] = *(const f32x4*)&sQt[mt * 16 + g * 4];
    f32x4 b2v[2], w3v[2];
    #pragma unroll
    for (int mt2 = 0; mt2 < 2; ++mt2) {
        b2v[mt2] = *(const f32x4*)&b2[h * 32 + mt2 * 16 + g * 4];
        w3v[mt2] = *(const f32x4*)&W3[h * 32 + mt2 * 16 + g * 4];
    }
    const float a1v = a1[h], a2v = a2[h], b3v = b3[h];
    ushort* bufA = uu.H1r[wave * 2];
    ushort* bufB = uu.H1r[wave * 2 + 1];

    // L1: keys-cvt + 8 MFMA + prelu + relay write into buf
    auto L1 = [&](const K4& kf, ushort* buf) {
        uint4v u0 = { cvtpk(kf.a.x, kf.a.y), cvtpk(kf.a.z, kf.a.w),
                      cvtpk(kf.b.x, kf.b.y), cvtpk(kf.b.z, kf.b.w) };
        uint4v u1 = { cvtpk(kf.c.x, kf.c.y), cvtpk(kf.c.z, kf.c.w),
                      cvtpk(kf.d.x, kf.d.y), cvtpk(kf.d.z, kf.d.w) };
        bf16x8 bk0 = __builtin_bit_cast(bf16x8, u0);
        bf16x8 bk1 = __builtin_bit_cast(bf16x8, u1);
        f32x4 acc[4] = { qtv[0], qtv[1], qtv[2], qtv[3] };
        #pragma unroll
        for (int mt = 0; mt < 4; ++mt)
            acc[mt] = __builtin_amdgcn_mfma_f32_16x16x32_bf16(wh[mt][0], bk0, acc[mt], 0, 0, 0);
        #pragma unroll
        for (int mt = 0; mt < 4; ++mt)
            acc[mt] = __builtin_amdgcn_mfma_f32_16x16x32_bf16(wh[mt][1], bk1, acc[mt], 0, 0, 0);
        #pragma unroll
        for (int mt = 0; mt < 4; ++mt) {
            float v0 = acc[mt][0]; v0 = v0 > 0.f ? v0 : a1v * v0;
            float v1 = acc[mt][1]; v1 = v1 > 0.f ? v1 : a1v * v1;
            float v2 = acc[mt][2]; v2 = v2 > 0.f ? v2 : a1v * v2;
            float v3 = acc[mt][3]; v3 = v3 > 0.f ? v3 : a1v * v3;
            *(uint2*)&buf[ln16 * PW + mt * 16 + g * 4] =
                make_uint2(cvtpk(v0, v1), cvtpk(v2, v3));
        }
    };

    // L2: relay read + 4 MFMA + prelu/dot W3 + score store
    auto L2 = [&](const ushort* buf, int st) {
        f32x4 acc2[2] = { b2v[0], b2v[1] };
        #pragma unroll
        for (int w = 0; w < 2; ++w) {
            bf16x8 Bh = *(const bf16x8*)&buf[ln16 * PW + w * 32 + g * 8];
            #pragma unroll
            for (int mt2 = 0; mt2 < 2; ++mt2)
                acc2[mt2] = __builtin_amdgcn_mfma_f32_16x16x32_bf16(w2f[w][mt2], Bh, acc2[mt2], 0, 0, 0);
        }
        float part = 0.f;
        #pragma unroll
        for (int mt2 = 0; mt2 < 2; ++mt2) {
            #pragma unroll
            for (int i = 0; i < 4; ++i) {
                float v = acc2[mt2][i];
                v = v > 0.f ? v : a2v * v;
                part += v * w3v[mt2][i];
            }
        }
        part += __shfl_xor(part, 16);
        part += __shfl_xor(part, 32);
        const int s = st * 16 + ln16;
        if (lane < 16 && s < 200) sSc[s] = part + b3v;
    };

    // ---- main loop: 2-stage pipeline, tiles {wave, wave+4, wave+8} (+12 on wave 0) ----
    {
        K4 k1 = loadKeys(wave + 4);
        L1(k0, bufA);
        K4 k2 = loadKeys(wave + 8);
        L1(k1, bufB);          // overlaps bufA relay round-trip
        L2(bufA, wave);
        if (wave == 0) {
            K4 k3 = loadKeys(12);
            L1(k2, bufA);
            L2(bufB, wave + 4);
            L1(k3, bufB);
            L2(bufA, wave + 8);
            L2(bufB, 12);
        } else {
            L1(k2, bufA);
            L2(bufB, wave + 4);
            L2(bufA, wave + 8);
        }
    }
    __syncthreads();

    // ---- masked softmax over 200 scores (wave 3 holds prefetched mask) ----
    if (wave == 3) {
        float v[4];
        float M = -INFINITY;
        #pragma unroll
        for (int c = 0; c < 4; ++c) {
            int s = lane + 64 * c;
            v[c] = (s < S && mval[c]) ? sSc[s] : -INFINITY;
            M = fmaxf(M, v[c]);
        }
        #pragma unroll
        for (int off = 32; off > 0; off >>= 1) M = fmaxf(M, __shfl_xor(M, off));
        float Z = 0.f, e[4];
        #pragma unroll
        for (int c = 0; c < 4; ++c) { e[c] = mval[c] ? __expf(v[c] - M) : 0.f; Z += e[c]; }
        #pragma unroll
        for (int off = 32; off > 0; off >>= 1) Z += __shfl_xor(Z, off);
        const float inv = Z > 0.f ? 1.f / Z : 0.f;
        #pragma unroll
        for (int c = 0; c < 4; ++c) { int s = lane + 64 * c; if (s < S) sSc[s] = e[c] * inv; }
    }
    __syncthreads();

    // ---- weighted key sum, vectorized: lane = d-quad (ln16), lane-group = s ----
    {
        const float* kb = keys + (size_t)b * S * D;
        const int s0 = wave * 4 + g;
        float4 acc = {0.f, 0.f, 0.f, 0.f};
        #pragma unroll 4
        for (int i = 0; i < 12; ++i) {
            const int s = i * 16 + s0;
            const float w = sSc[s];
            float4 kv = *(const float4*)&kb[s * 64 + 4 * ln16];
            acc.x += w * kv.x; acc.y += w * kv.y;
            acc.z += w * kv.z; acc.w += w * kv.w;
        }
        {   // tail s = 192..199 (waves 0,1 only; wave-uniform branch)
            const int s = 192 + s0;
            if (s < 200) {
                const float w = sSc[s];
                float4 kv = *(const float4*)&kb[s * 64 + 4 * ln16];
                acc.x += w * kv.x; acc.y += w * kv.y;
                acc.z += w * kv.z; acc.w += w * kv.w;
            }
        }
        // reduce over the 4 lane-groups (s-subsets)
        acc.x += __shfl_xor(acc.x, 16); acc.y += __shfl_xor(acc.y, 16);
        acc.z += __shfl_xor(acc.z, 16); acc.w += __shfl_xor(acc.w, 16);
        acc.x += __shfl_xor(acc.x, 32); acc.y += __shfl_xor(acc.y, 32);
        acc.z += __shfl_xor(acc.z, 32); acc.w += __shfl_xor(acc.w, 32);
        if (lane < 16) *(float4*)&sQp[wave][lane * 4] = acc;
    }
    __syncthreads();
    if (t < 64)
        outh[((size_t)b * H + h) * D + t] = sQp[0][t] + sQp[1][t] + sQp[2][t] + sQp[3][t];
}

// ---------------------------------------------------------------------------
// Projection: out[b] = (mean_h outh[b,h,:]) @ Wo + bo.  4 b-rows per block.
// ---------------------------------------------------------------------------
__global__ __launch_bounds__(256) void proj_kernel(
    const float* __restrict__ outh, const float* __restrict__ Wo,
    const float* __restrict__ bo, float* __restrict__ out)
{
    __shared__ float comb[4][64];
    const int t = threadIdx.x, bb = t >> 6, j = t & 63;
    const size_t b = (size_t)blockIdx.x * 4 + bb;

    const float* oh = outh + b * H * D;
    comb[bb][j] = 0.25f * (oh[j] + oh[64 + j] + oh[128 + j] + oh[192 + j]);
    __syncthreads();

    float o = bo[j];
    #pragma unroll 8
    for (int d = 0; d < 64; ++d)
        o += comb[bb][d] * Wo[d * 64 + j];
    out[b * D + j] = o;
}

// ---------------------------------------------------------------------------
extern "C" void kernel_launch(void* const* d_in, const int* in_sizes, int n_in,
                              void* d_out, int out_size, void* d_ws, size_t ws_size,
                              hipStream_t stream) {
    const float* query = (const float*)d_in[0];
    const float* keys  = (const float*)d_in[1];
    const int*   mask  = (const int*)d_in[2];
    const float* W1 = (const float*)d_in[3];
    const float* b1 = (const float*)d_in[4];
    const float* a1 = (const float*)d_in[5];
    const float* W2 = (const float*)d_in[6];
    const float* b2 = (const float*)d_in[7];
    const float* a2 = (const float*)d_in[8];
    const float* W3 = (const float*)d_in[9];
    const float* b3 = (const float*)d_in[10];
    const float* Wo = (const float*)d_in[11];
    const float* bo = (const float*)d_in[12];

    float* out  = (float*)d_out;
    float* outh = (float*)d_ws;   // B*H*D floats = 2 MB

    score_attend_kernel<<<dim3(B * H), 256, 0, stream>>>(
        query, keys, mask, W1, b1, a1, W2, b2, a2, W3, b3, outh);
    proj_kernel<<<dim3(B / 4), 256, 0, stream>>>(outh, Wo, bo, out);
}

// Round 11
// 88.911 us; speedup vs baseline: 1.4047x; 1.2271x over previous
//
#include <hip/hip_runtime.h>
#include <math.h>

constexpr int B  = 2048;
constexpr int S  = 200;
constexpr int D  = 64;
constexpr int H  = 4;
constexpr int H1 = 64;
constexpr int H2 = 32;
constexpr int F  = 256;

constexpr int PK = 72;   // ushort pitch: 144 B rows (16B multiple), ~2-way banks

typedef short bf16x8 __attribute__((ext_vector_type(8)));
typedef float f32x4  __attribute__((ext_vector_type(4)));
typedef unsigned uint4v __attribute__((ext_vector_type(4)));

__device__ __forceinline__ unsigned cvtpk(float a, float b) {
    unsigned r;
    asm volatile("v_cvt_pk_bf16_f32 %0, %1, %2" : "=v"(r) : "v"(a), "v"(b));
    return r;
}
__device__ __forceinline__ float lo16f(unsigned w) { return __builtin_bit_cast(float, w << 16); }
__device__ __forceinline__ float hi16f(unsigned w) { return __builtin_bit_cast(float, w & 0xffff0000u); }

// ---------------------------------------------------------------------------
// One block per batch row b; 4 waves; wave w owns head h=w end-to-end.
// Single barrier (keys staging). Everything else wave-private.
//   Weff[d][k] = W1[h,d,k] + W1[h,192+d,k] + q_d * W1[h,128+d,k]   (hi bf16)
//   qt[k]      = b1[h,k] + sum_d q_d*(W1[h,64+d,k] - W1[h,192+d,k])
//   h1T = WeffT @ keysT (qt as C-init) -> prelu -> relay (wave-private LDS)
//   -> W2 MFMA (b2 as C-init) -> prelu -> dot W3 -> scores -> softmax ->
//   attend from LDS bf16 keys -> outh[b,h,:].
// ---------------------------------------------------------------------------
__global__ __launch_bounds__(256, 4) void fused_b_kernel(
    const float* __restrict__ query, const float* __restrict__ keys,
    const int* __restrict__ mask,
    const float* __restrict__ W1, const float* __restrict__ b1, const float* __restrict__ a1,
    const float* __restrict__ W2, const float* __restrict__ b2, const float* __restrict__ a2,
    const float* __restrict__ W3, const float* __restrict__ b3,
    float* __restrict__ outh)
{
    __shared__ ushort sK[208 * PK];       // keys bf16 [s][d], shared by all waves
    __shared__ ushort sW[4][64 * PK];     // per-wave WeffT [k][d]; rows 0..15 reused as relay
    __shared__ float  sQ4[4][64];         // per-wave q copy (broadcast source)
    __shared__ float  sQt[4][64];         // per-wave qt
    __shared__ float  sSc[4][208];        // per-wave scores -> weights

    const int b    = blockIdx.x;
    const int t    = threadIdx.x;
    const int lane = t & 63;
    const int h    = t >> 6;              // wave = head
    const int g    = lane >> 4;
    const int ln16 = lane & 15;

    // ---- early independent global loads (in flight under staging/build) ----
    int mval[4];
    #pragma unroll
    for (int c = 0; c < 4; ++c) {
        int s = lane + 64 * c;
        mval[c] = (s < S) ? mask[(size_t)b * S + s] : 0;
    }

    bf16x8 w2f[2][2];
    {
        const float* w2p = W2 + (size_t)h * H1 * H2;   // [k2][m]
        #pragma unroll
        for (int w = 0; w < 2; ++w)
            #pragma unroll
            for (int mt2 = 0; mt2 < 2; ++mt2) {
                const int m = 16 * mt2 + ln16, k20 = 32 * w + 8 * g;
                float v0 = w2p[(k20 + 0) * 32 + m], v1 = w2p[(k20 + 1) * 32 + m];
                float v2 = w2p[(k20 + 2) * 32 + m], v3 = w2p[(k20 + 3) * 32 + m];
                float v4 = w2p[(k20 + 4) * 32 + m], v5 = w2p[(k20 + 5) * 32 + m];
                float v6 = w2p[(k20 + 6) * 32 + m], v7 = w2p[(k20 + 7) * 32 + m];
                uint4v u = { cvtpk(v0, v1), cvtpk(v2, v3), cvtpk(v4, v5), cvtpk(v6, v7) };
                w2f[w][mt2] = __builtin_bit_cast(bf16x8, u);
            }
    }
    f32x4 b2v[2], w3v[2];
    #pragma unroll
    for (int mt2 = 0; mt2 < 2; ++mt2) {
        b2v[mt2] = *(const f32x4*)&b2[h * 32 + mt2 * 16 + 4 * g];
        w3v[mt2] = *(const f32x4*)&W3[h * 32 + mt2 * 16 + 4 * g];
    }

    // ---- per-wave q copy ----
    sQ4[h][lane] = query[(size_t)b * D + lane];

    // ---- cooperative keys staging (bf16), 3200 float4s ----
    {
        const float4* k4 = (const float4*)(keys + (size_t)b * S * D);
        for (int idx = t; idx < S * D / 4; idx += 256) {
            float4 v = k4[idx];
            int s = idx >> 4, dc = (idx & 15) * 4;
            *(uint2*)&sK[s * PK + dc] = make_uint2(cvtpk(v.x, v.y), cvtpk(v.z, v.w));
        }
        for (int i = t; i < 8 * PK / 2; i += 256)
            ((unsigned*)&sK[200 * PK])[i] = 0;   // zero pad rows 200..207
    }

    // ---- per-wave Weff build (coalesced W1 reads, q broadcast from own LDS) ----
    {
        const float* w1h = W1 + (size_t)h * F * H1;
        const int l = lane;
        float qtp = 0.f;
        #pragma unroll 4
        for (int dc = 0; dc < 16; ++dc) {
            f32x4 qv = *(const f32x4*)&sQ4[h][dc * 4];   // uniform addr -> broadcast
            float w4[4];
            #pragma unroll
            for (int j = 0; j < 4; ++j) {
                const int d = dc * 4 + j;
                float A = w1h[d * 64 + l];
                float Bv = w1h[(64 + d) * 64 + l];
                float C = w1h[(128 + d) * 64 + l];
                float Dv = w1h[(192 + d) * 64 + l];
                w4[j] = A + Dv + qv[j] * C;
                qtp += qv[j] * (Bv - Dv);
            }
            *(uint2*)&sW[h][l * PK + dc * 4] =
                make_uint2(cvtpk(w4[0], w4[1]), cvtpk(w4[2], w4[3]));
        }
        sQt[h][l] = qtp + b1[h * 64 + l];
    }

    // ---- hoist fragments (own region, lgkm-ordered within wave) ----
    bf16x8 wh[4][2];
    #pragma unroll
    for (int mt = 0; mt < 4; ++mt)
        #pragma unroll
        for (int kk = 0; kk < 2; ++kk)
            wh[mt][kk] = *(const bf16x8*)&sW[h][(mt * 16 + ln16) * PK + kk * 32 + 8 * g];
    f32x4 qtv[4];
    #pragma unroll
    for (int mt = 0; mt < 4; ++mt) qtv[mt] = *(const f32x4*)&sQt[h][mt * 16 + 4 * g];

    const float a1v = a1[h], a2v = a2[h], b3v = b3[h];

    __syncthreads();   // the ONLY barrier: sK ready for all waves

    ushort* relay = &sW[h][0];   // wave-private, Weff rows 0..15 now dead

    // ---- main loop: all 13 s-tiles on this wave, no syncs ----
    for (int st = 0; st < 13; ++st) {
        bf16x8 bk0 = *(const bf16x8*)&sK[(st * 16 + ln16) * PK + 0  + 8 * g];
        bf16x8 bk1 = *(const bf16x8*)&sK[(st * 16 + ln16) * PK + 32 + 8 * g];

        f32x4 acc[4] = { qtv[0], qtv[1], qtv[2], qtv[3] };
        #pragma unroll
        for (int mt = 0; mt < 4; ++mt)
            acc[mt] = __builtin_amdgcn_mfma_f32_16x16x32_bf16(wh[mt][0], bk0, acc[mt], 0, 0, 0);
        #pragma unroll
        for (int mt = 0; mt < 4; ++mt)
            acc[mt] = __builtin_amdgcn_mfma_f32_16x16x32_bf16(wh[mt][1], bk1, acc[mt], 0, 0, 0);

        #pragma unroll
        for (int mt = 0; mt < 4; ++mt) {
            float v0 = acc[mt][0]; v0 = v0 > 0.f ? v0 : a1v * v0;
            float v1 = acc[mt][1]; v1 = v1 > 0.f ? v1 : a1v * v1;
            float v2 = acc[mt][2]; v2 = v2 > 0.f ? v2 : a1v * v2;
            float v3 = acc[mt][3]; v3 = v3 > 0.f ? v3 : a1v * v3;
            *(uint2*)&relay[ln16 * PK + mt * 16 + 4 * g] =
                make_uint2(cvtpk(v0, v1), cvtpk(v2, v3));
        }

        f32x4 acc2[2] = { b2v[0], b2v[1] };
        #pragma unroll
        for (int w = 0; w < 2; ++w) {
            bf16x8 Bh = *(const bf16x8*)&relay[ln16 * PK + w * 32 + 8 * g];
            #pragma unroll
            for (int mt2 = 0; mt2 < 2; ++mt2)
                acc2[mt2] = __builtin_amdgcn_mfma_f32_16x16x32_bf16(w2f[w][mt2], Bh, acc2[mt2], 0, 0, 0);
        }

        float part = 0.f;
        #pragma unroll
        for (int mt2 = 0; mt2 < 2; ++mt2) {
            #pragma unroll
            for (int i = 0; i < 4; ++i) {
                float v = acc2[mt2][i];
                v = v > 0.f ? v : a2v * v;
                part += v * w3v[mt2][i];
            }
        }
        part += __shfl_xor(part, 16);
        part += __shfl_xor(part, 32);
        const int s = st * 16 + ln16;
        if (lane < 16 && s < 200) sSc[h][s] = part + b3v;
    }

    // ---- per-wave masked softmax (scores written by this wave) ----
    {
        float v[4];
        float M = -INFINITY;
        #pragma unroll
        for (int c = 0; c < 4; ++c) {
            int s = lane + 64 * c;
            v[c] = (s < S && mval[c]) ? sSc[h][s] : -INFINITY;
            M = fmaxf(M, v[c]);
        }
        #pragma unroll
        for (int off = 32; off > 0; off >>= 1) M = fmaxf(M, __shfl_xor(M, off));
        float Z = 0.f, e[4];
        #pragma unroll
        for (int c = 0; c < 4; ++c) { e[c] = mval[c] ? __expf(v[c] - M) : 0.f; Z += e[c]; }
        #pragma unroll
        for (int off = 32; off > 0; off >>= 1) Z += __shfl_xor(Z, off);
        const float inv = Z > 0.f ? 1.f / Z : 0.f;
        #pragma unroll
        for (int c = 0; c < 4; ++c) { int s = lane + 64 * c; if (s < S) sSc[h][s] = e[c] * inv; }
    }

    // ---- per-wave attend from LDS bf16 keys: lane = (s-group, d-quad) ----
    {
        const int sg = lane >> 4, dq = ln16;
        float ax = 0.f, ay = 0.f, az = 0.f, aw = 0.f;
        #pragma unroll 5
        for (int i = 0; i < 50; ++i) {
            const int s = sg * 50 + i;
            const float w = sSc[h][s];            // uniform per 16-lane group
            uint2 kv = *(const uint2*)&sK[s * PK + 4 * dq];
            ax += w * lo16f(kv.x); ay += w * hi16f(kv.x);
            az += w * lo16f(kv.y); aw += w * hi16f(kv.y);
        }
        ax += __shfl_xor(ax, 16); ay += __shfl_xor(ay, 16);
        az += __shfl_xor(az, 16); aw += __shfl_xor(aw, 16);
        ax += __shfl_xor(ax, 32); ay += __shfl_xor(ay, 32);
        az += __shfl_xor(az, 32); aw += __shfl_xor(aw, 32);
        if (lane < 16) {
            float4 o = { ax, ay, az, aw };
            *(float4*)&outh[((size_t)b * H + h) * D + 4 * dq] = o;
        }
    }
}

// ---------------------------------------------------------------------------
// Projection: out[b] = (mean_h outh[b,h,:]) @ Wo + bo.  4 b-rows per block.
// ---------------------------------------------------------------------------
__global__ __launch_bounds__(256) void proj_kernel(
    const float* __restrict__ outh, const float* __restrict__ Wo,
    const float* __restrict__ bo, float* __restrict__ out)
{
    __shared__ float comb[4][64];
    const int t = threadIdx.x, bb = t >> 6, j = t & 63;
    const size_t b = (size_t)blockIdx.x * 4 + bb;

    const float* oh = outh + b * H * D;
    comb[bb][j] = 0.25f * (oh[j] + oh[64 + j] + oh[128 + j] + oh[192 + j]);
    __syncthreads();

    float o = bo[j];
    #pragma unroll 8
    for (int d = 0; d < 64; ++d)
        o += comb[bb][d] * Wo[d * 64 + j];
    out[b * D + j] = o;
}

// ---------------------------------------------------------------------------
extern "C" void kernel_launch(void* const* d_in, const int* in_sizes, int n_in,
                              void* d_out, int out_size, void* d_ws, size_t ws_size,
                              hipStream_t stream) {
    const float* query = (const float*)d_in[0];
    const float* keys  = (const float*)d_in[1];
    const int*   mask  = (const int*)d_in[2];
    const float* W1 = (const float*)d_in[3];
    const float* b1 = (const float*)d_in[4];
    const float* a1 = (const float*)d_in[5];
    const float* W2 = (const float*)d_in[6];
    const float* b2 = (const float*)d_in[7];
    const float* a2 = (const float*)d_in[8];
    const float* W3 = (const float*)d_in[9];
    const float* b3 = (const float*)d_in[10];
    const float* Wo = (const float*)d_in[11];
    const float* bo = (const float*)d_in[12];

    float* out  = (float*)d_out;
    float* outh = (float*)d_ws;   // B*H*D floats = 2 MB

    fused_b_kernel<<<dim3(B), 256, 0, stream>>>(
        query, keys, mask, W1, b1, a1, W2, b2, a2, W3, b3, outh);
    proj_kernel<<<dim3(B / 4), 256, 0, stream>>>(outh, Wo, bo, out);
}

// Round 12
// 69.900 us; speedup vs baseline: 1.7867x; 1.2720x over previous
//
#include <hip/hip_runtime.h>
#include <math.h>

constexpr int B  = 2048;
constexpr int S  = 200;
constexpr int D  = 64;
constexpr int H  = 4;
constexpr int H1 = 64;
constexpr int H2 = 32;
constexpr int F  = 256;

constexpr int PK = 72;   // ushort pitch: 144 B rows (16B multiple), ~2-way banks

typedef short bf16x8 __attribute__((ext_vector_type(8)));
typedef float f32x4  __attribute__((ext_vector_type(4)));
typedef unsigned uint4v __attribute__((ext_vector_type(4)));

__device__ __forceinline__ unsigned cvtpk(float a, float b) {
    unsigned r;
    asm volatile("v_cvt_pk_bf16_f32 %0, %1, %2" : "=v"(r) : "v"(a), "v"(b));
    return r;
}
__device__ __forceinline__ float lo16f(unsigned w) { return __builtin_bit_cast(float, w << 16); }
__device__ __forceinline__ float hi16f(unsigned w) { return __builtin_bit_cast(float, w & 0xffff0000u); }

// ---- workspace layout ----
constexpr size_t OUTH_OFF = 0;                                   // B*H*D f32 = 2 MB
constexpr size_t SAD_OFF  = 2u * 1024 * 1024;                    // 4h * 4096 f32 = 64 KB
constexpr size_t SC_OFF   = SAD_OFF + 4 * 4096 * 4;
constexpr size_t SBD_OFF  = SC_OFF  + 4 * 4096 * 4;
constexpr size_t W2I_OFF  = SBD_OFF + 4 * 4096 * 4;              // 4h * 2048 ushort = 16 KB

// ---------------------------------------------------------------------------
// Build kernel (per-head constants, run once per launch, ~208 KB L2-resident):
// fragment-ordered images of A+D, C, B-D (f32) and W2 (bf16).
// Slot (f, l): f = kk*4+mt; k = 16*mt+(l&15); d0 = 32*kk+8*(l>>4); 8 d values.
// ---------------------------------------------------------------------------
__global__ __launch_bounds__(256) void build_kernel(
    const float* __restrict__ W1, const float* __restrict__ W2,
    float* __restrict__ sad, float* __restrict__ sc, float* __restrict__ sbd,
    ushort* __restrict__ w2i)
{
    const int h = blockIdx.x;
    const int t = threadIdx.x;
    const float* w1h = W1 + (size_t)h * F * H1;

    #pragma unroll
    for (int half = 0; half < 2; ++half) {
        const int sl = half * 256 + t;          // 0..511
        const int f  = sl >> 6, l = sl & 63;
        const int mt = f & 3, kk = f >> 2;
        const int k  = 16 * mt + (l & 15);
        const int d0 = 32 * kk + ((l >> 4) << 3);
        float vs[8], vc[8], vb[8];
        #pragma unroll
        for (int j = 0; j < 8; ++j) {
            const int d = d0 + j;
            float A  = w1h[d * 64 + k];
            float Bv = w1h[(64 + d) * 64 + k];
            float C  = w1h[(128 + d) * 64 + k];
            float Dv = w1h[(192 + d) * 64 + k];
            vs[j] = A + Dv; vc[j] = C; vb[j] = Bv - Dv;
        }
        const size_t off = ((size_t)h * 512 + sl) * 8;
        *(f32x4*)&sad[off]     = *(f32x4*)&vs[0];
        *(f32x4*)&sad[off + 4] = *(f32x4*)&vs[4];
        *(f32x4*)&sc [off]     = *(f32x4*)&vc[0];
        *(f32x4*)&sc [off + 4] = *(f32x4*)&vc[4];
        *(f32x4*)&sbd[off]     = *(f32x4*)&vb[0];
        *(f32x4*)&sbd[off + 4] = *(f32x4*)&vb[4];
    }

    {   // W2 fragment image: f2 = w*2+mt2; m = 16*mt2+(l&15); k20 = 32*w+8*(l>>4)
        const int f2 = t >> 6, l = t & 63;
        const int mt2 = f2 & 1, w = f2 >> 1;
        const int m = 16 * mt2 + (l & 15), k20 = 32 * w + ((l >> 4) << 3);
        const float* w2h = W2 + (size_t)h * H1 * H2;
        uint4v u = { cvtpk(w2h[(k20 + 0) * 32 + m], w2h[(k20 + 1) * 32 + m]),
                     cvtpk(w2h[(k20 + 2) * 32 + m], w2h[(k20 + 3) * 32 + m]),
                     cvtpk(w2h[(k20 + 4) * 32 + m], w2h[(k20 + 5) * 32 + m]),
                     cvtpk(w2h[(k20 + 6) * 32 + m], w2h[(k20 + 7) * 32 + m]) };
        *(uint4v*)&w2i[((size_t)h * 4 + f2) * 512 + l * 8] = u;
    }
}

// ---------------------------------------------------------------------------
// One block per batch row b; 4 waves; wave = head, end-to-end; single barrier.
//   Weff_frag = SAD + q∘SC (f32 in registers, one bf16 rounding)
//   qt[k]     = b1[k] + sum_d q_d*(B-D)[d][k]  (register dots + shfl reduce)
//   h1T = WeffT @ keysT (qt as C-init) -> prelu -> wave-private relay ->
//   W2 MFMA (b2 as C-init) -> prelu -> dot W3 -> scores -> softmax ->
//   attend from LDS bf16 keys -> outh[b,h,:].
// ---------------------------------------------------------------------------
__global__ __launch_bounds__(256, 3) void fused_b_kernel(
    const float* __restrict__ query, const float* __restrict__ keys,
    const int* __restrict__ mask,
    const float* __restrict__ sad, const float* __restrict__ sc,
    const float* __restrict__ sbd, const ushort* __restrict__ w2i,
    const float* __restrict__ b1, const float* __restrict__ a1,
    const float* __restrict__ b2, const float* __restrict__ a2,
    const float* __restrict__ W3, const float* __restrict__ b3,
    float* __restrict__ outh)
{
    __shared__ ushort sK[208 * PK];        // keys bf16 [s][d]
    __shared__ ushort relay[4][16 * PK];   // per-wave h1 relay
    __shared__ float  sSc[4][208];         // per-wave scores -> weights

    const int b    = blockIdx.x;
    const int t    = threadIdx.x;
    const int lane = t & 63;
    const int h    = t >> 6;               // wave = head
    const int g    = lane >> 4;
    const int ln16 = lane & 15;

    // ---- mask prefetch ----
    int mval[4];
    #pragma unroll
    for (int c = 0; c < 4; ++c) {
        int s = lane + 64 * c;
        mval[c] = (s < S) ? mask[(size_t)b * S + s] : 0;
    }

    // ---- cooperative keys staging (bf16) ----
    {
        const float4* k4 = (const float4*)(keys + (size_t)b * S * D);
        for (int idx = t; idx < S * D / 4; idx += 256) {
            float4 v = k4[idx];
            int s = idx >> 4, dc = (idx & 15) * 4;
            *(uint2*)&sK[s * PK + dc] = make_uint2(cvtpk(v.x, v.y), cvtpk(v.z, v.w));
        }
        for (int i = t; i < 8 * PK / 2; i += 256)
            ((unsigned*)&sK[200 * PK])[i] = 0;   // zero pad rows 200..207
    }

    // ---- register Weff build from fragment images + q ----
    const float* qb = query + (size_t)b * D;
    bf16x8 wh[4][2];
    float qtp0 = 0.f, qtp1 = 0.f, qtp2 = 0.f, qtp3 = 0.f;
    #pragma unroll
    for (int kk = 0; kk < 2; ++kk) {
        const int d0 = 32 * kk + 8 * g;
        f32x4 q0 = *(const f32x4*)&qb[d0];
        f32x4 q1 = *(const f32x4*)&qb[d0 + 4];
        #pragma unroll
        for (int mt = 0; mt < 4; ++mt) {
            const int f = kk * 4 + mt;
            const size_t off = ((size_t)h * 512 + f * 64 + lane) * 8;
            f32x4 s0 = *(const f32x4*)&sad[off], s1 = *(const f32x4*)&sad[off + 4];
            f32x4 c0 = *(const f32x4*)&sc [off], c1 = *(const f32x4*)&sc [off + 4];
            f32x4 bd0 = *(const f32x4*)&sbd[off], bd1 = *(const f32x4*)&sbd[off + 4];
            float w0 = s0[0] + q0[0] * c0[0], w1 = s0[1] + q0[1] * c0[1];
            float w2 = s0[2] + q0[2] * c0[2], w3 = s0[3] + q0[3] * c0[3];
            float w4 = s1[0] + q1[0] * c1[0], w5 = s1[1] + q1[1] * c1[1];
            float w6 = s1[2] + q1[2] * c1[2], w7 = s1[3] + q1[3] * c1[3];
            uint4v u = { cvtpk(w0, w1), cvtpk(w2, w3), cvtpk(w4, w5), cvtpk(w6, w7) };
            wh[mt][kk] = __builtin_bit_cast(bf16x8, u);
            float d = q0[0]*bd0[0] + q0[1]*bd0[1] + q0[2]*bd0[2] + q0[3]*bd0[3]
                    + q1[0]*bd1[0] + q1[1]*bd1[1] + q1[2]*bd1[2] + q1[3]*bd1[3];
            if (mt == 0) qtp0 += d; else if (mt == 1) qtp1 += d;
            else if (mt == 2) qtp2 += d; else qtp3 += d;
        }
    }
    // reduce qt partials over the 4 lane-groups; lane (ln16) holds qt[16mt+ln16]
    qtp0 += __shfl_xor(qtp0, 16); qtp0 += __shfl_xor(qtp0, 32);
    qtp1 += __shfl_xor(qtp1, 16); qtp1 += __shfl_xor(qtp1, 32);
    qtp2 += __shfl_xor(qtp2, 16); qtp2 += __shfl_xor(qtp2, 32);
    qtp3 += __shfl_xor(qtp3, 16); qtp3 += __shfl_xor(qtp3, 32);
    // redistribute to C-layout: qtv[mt][i] = qt[16mt+4g+i] + b1
    f32x4 qtv[4];
    #pragma unroll
    for (int mt = 0; mt < 4; ++mt) {
        float src = (mt == 0) ? qtp0 : (mt == 1) ? qtp1 : (mt == 2) ? qtp2 : qtp3;
        f32x4 b1v = *(const f32x4*)&b1[h * 64 + mt * 16 + 4 * g];
        f32x4 v;
        #pragma unroll
        for (int i = 0; i < 4; ++i) v[i] = __shfl(src, 4 * g + i) + b1v[i];
        qtv[mt] = v;
    }

    // ---- W2 fragments + layer-2/3 constants ----
    bf16x8 w2f[2][2];
    #pragma unroll
    for (int w = 0; w < 2; ++w)
        #pragma unroll
        for (int mt2 = 0; mt2 < 2; ++mt2)
            w2f[w][mt2] = *(const bf16x8*)&w2i[((size_t)h * 4 + w * 2 + mt2) * 512 + lane * 8];
    f32x4 b2v[2], w3v[2];
    #pragma unroll
    for (int mt2 = 0; mt2 < 2; ++mt2) {
        b2v[mt2] = *(const f32x4*)&b2[h * 32 + mt2 * 16 + 4 * g];
        w3v[mt2] = *(const f32x4*)&W3[h * 32 + mt2 * 16 + 4 * g];
    }
    const float a1v = a1[h], a2v = a2[h], b3v = b3[h];

    __syncthreads();   // the ONLY barrier: sK ready

    ushort* myR = relay[h];

    // ---- main loop: all 13 s-tiles on this wave, no syncs ----
    for (int st = 0; st < 13; ++st) {
        bf16x8 bk0 = *(const bf16x8*)&sK[(st * 16 + ln16) * PK + 0  + 8 * g];
        bf16x8 bk1 = *(const bf16x8*)&sK[(st * 16 + ln16) * PK + 32 + 8 * g];

        f32x4 acc[4] = { qtv[0], qtv[1], qtv[2], qtv[3] };
        #pragma unroll
        for (int mt = 0; mt < 4; ++mt)
            acc[mt] = __builtin_amdgcn_mfma_f32_16x16x32_bf16(wh[mt][0], bk0, acc[mt], 0, 0, 0);
        #pragma unroll
        for (int mt = 0; mt < 4; ++mt)
            acc[mt] = __builtin_amdgcn_mfma_f32_16x16x32_bf16(wh[mt][1], bk1, acc[mt], 0, 0, 0);

        #pragma unroll
        for (int mt = 0; mt < 4; ++mt) {
            float v0 = acc[mt][0]; v0 = v0 > 0.f ? v0 : a1v * v0;
            float v1 = acc[mt][1]; v1 = v1 > 0.f ? v1 : a1v * v1;
            float v2 = acc[mt][2]; v2 = v2 > 0.f ? v2 : a1v * v2;
            float v3 = acc[mt][3]; v3 = v3 > 0.f ? v3 : a1v * v3;
            *(uint2*)&myR[ln16 * PK + mt * 16 + 4 * g] =
                make_uint2(cvtpk(v0, v1), cvtpk(v2, v3));
        }

        f32x4 acc2[2] = { b2v[0], b2v[1] };
        #pragma unroll
        for (int w = 0; w < 2; ++w) {
            bf16x8 Bh = *(const bf16x8*)&myR[ln16 * PK + w * 32 + 8 * g];
            #pragma unroll
            for (int mt2 = 0; mt2 < 2; ++mt2)
                acc2[mt2] = __builtin_amdgcn_mfma_f32_16x16x32_bf16(w2f[w][mt2], Bh, acc2[mt2], 0, 0, 0);
        }

        float part = 0.f;
        #pragma unroll
        for (int mt2 = 0; mt2 < 2; ++mt2) {
            #pragma unroll
            for (int i = 0; i < 4; ++i) {
                float v = acc2[mt2][i];
                v = v > 0.f ? v : a2v * v;
                part += v * w3v[mt2][i];
            }
        }
        part += __shfl_xor(part, 16);
        part += __shfl_xor(part, 32);
        const int s = st * 16 + ln16;
        if (lane < 16 && s < 200) sSc[h][s] = part + b3v;
    }

    // ---- per-wave masked softmax ----
    {
        float v[4];
        float M = -INFINITY;
        #pragma unroll
        for (int c = 0; c < 4; ++c) {
            int s = lane + 64 * c;
            v[c] = (s < S && mval[c]) ? sSc[h][s] : -INFINITY;
            M = fmaxf(M, v[c]);
        }
        #pragma unroll
        for (int off = 32; off > 0; off >>= 1) M = fmaxf(M, __shfl_xor(M, off));
        float Z = 0.f, e[4];
        #pragma unroll
        for (int c = 0; c < 4; ++c) { e[c] = mval[c] ? __expf(v[c] - M) : 0.f; Z += e[c]; }
        #pragma unroll
        for (int off = 32; off > 0; off >>= 1) Z += __shfl_xor(Z, off);
        const float inv = Z > 0.f ? 1.f / Z : 0.f;
        #pragma unroll
        for (int c = 0; c < 4; ++c) { int s = lane + 64 * c; if (s < S) sSc[h][s] = e[c] * inv; }
    }

    // ---- per-wave attend from LDS bf16 keys ----
    {
        const int sg = lane >> 4, dq = ln16;
        float ax = 0.f, ay = 0.f, az = 0.f, aw = 0.f;
        #pragma unroll 5
        for (int i = 0; i < 50; ++i) {
            const int s = sg * 50 + i;
            const float w = sSc[h][s];
            uint2 kv = *(const uint2*)&sK[s * PK + 4 * dq];
            ax += w * lo16f(kv.x); ay += w * hi16f(kv.x);
            az += w * lo16f(kv.y); aw += w * hi16f(kv.y);
        }
        ax += __shfl_xor(ax, 16); ay += __shfl_xor(ay, 16);
        az += __shfl_xor(az, 16); aw += __shfl_xor(aw, 16);
        ax += __shfl_xor(ax, 32); ay += __shfl_xor(ay, 32);
        az += __shfl_xor(az, 32); aw += __shfl_xor(aw, 32);
        if (lane < 16) {
            float4 o = { ax, ay, az, aw };
            *(float4*)&outh[((size_t)b * H + h) * D + 4 * dq] = o;
        }
    }
}

// ---------------------------------------------------------------------------
// Projection: out[b] = (mean_h outh[b,h,:]) @ Wo + bo.  4 b-rows per block.
// ---------------------------------------------------------------------------
__global__ __launch_bounds__(256) void proj_kernel(
    const float* __restrict__ outh, const float* __restrict__ Wo,
    const float* __restrict__ bo, float* __restrict__ out)
{
    __shared__ float comb[4][64];
    const int t = threadIdx.x, bb = t >> 6, j = t & 63;
    const size_t b = (size_t)blockIdx.x * 4 + bb;

    const float* oh = outh + b * H * D;
    comb[bb][j] = 0.25f * (oh[j] + oh[64 + j] + oh[128 + j] + oh[192 + j]);
    __syncthreads();

    float o = bo[j];
    #pragma unroll 8
    for (int d = 0; d < 64; ++d)
        o += comb[bb][d] * Wo[d * 64 + j];
    out[b * D + j] = o;
}

// ---------------------------------------------------------------------------
extern "C" void kernel_launch(void* const* d_in, const int* in_sizes, int n_in,
                              void* d_out, int out_size, void* d_ws, size_t ws_size,
                              hipStream_t stream) {
    const float* query = (const float*)d_in[0];
    const float* keys  = (const float*)d_in[1];
    const int*   mask  = (const int*)d_in[2];
    const float* W1 = (const float*)d_in[3];
    const float* b1 = (const float*)d_in[4];
    const float* a1 = (const float*)d_in[5];
    const float* W2 = (const float*)d_in[6];
    const float* b2 = (const float*)d_in[7];
    const float* a2 = (const float*)d_in[8];
    const float* W3 = (const float*)d_in[9];
    const float* b3 = (const float*)d_in[10];
    const float* Wo = (const float*)d_in[11];
    const float* bo = (const float*)d_in[12];

    float* out  = (float*)d_out;
    char*  ws   = (char*)d_ws;
    float* outh = (float*)(ws + OUTH_OFF);
    float* sad  = (float*)(ws + SAD_OFF);
    float* sc   = (float*)(ws + SC_OFF);
    float* sbd  = (float*)(ws + SBD_OFF);
    ushort* w2i = (ushort*)(ws + W2I_OFF);

    build_kernel<<<dim3(H), 256, 0, stream>>>(W1, W2, sad, sc, sbd, w2i);
    fused_b_kernel<<<dim3(B), 256, 0, stream>>>(
        query, keys, mask, sad, sc, sbd, w2i, b1, a1, b2, a2, W3, b3, outh);
    proj_kernel<<<dim3(B / 4), 256, 0, stream>>>(outh, Wo, bo, out);
}

// Round 13
// 66.266 us; speedup vs baseline: 1.8847x; 1.0548x over previous
//
#include <hip/hip_runtime.h>
#include <math.h>

constexpr int B  = 2048;
constexpr int S  = 200;
constexpr int D  = 64;
constexpr int H  = 4;
constexpr int H1 = 64;
constexpr int H2 = 32;
constexpr int F  = 256;

constexpr int PK = 72;   // ushort pitch: 144 B rows (16B multiple), ~2-way banks

typedef short bf16x8 __attribute__((ext_vector_type(8)));
typedef float f32x4  __attribute__((ext_vector_type(4)));
typedef unsigned uint4v __attribute__((ext_vector_type(4)));

__device__ __forceinline__ unsigned cvtpk(float a, float b) {
    unsigned r;
    asm volatile("v_cvt_pk_bf16_f32 %0, %1, %2" : "=v"(r) : "v"(a), "v"(b));
    return r;
}
__device__ __forceinline__ float lo16f(unsigned w) { return __builtin_bit_cast(float, w << 16); }
__device__ __forceinline__ float hi16f(unsigned w) { return __builtin_bit_cast(float, w & 0xffff0000u); }

// ---- workspace layout (per-head constant images only, ~208 KB, L2-resident) ----
constexpr size_t SAD_OFF = 0;                        // 4h * 4096 f32
constexpr size_t SC_OFF  = SAD_OFF + 4 * 4096 * 4;
constexpr size_t SBD_OFF = SC_OFF  + 4 * 4096 * 4;
constexpr size_t W2I_OFF = SBD_OFF + 4 * 4096 * 4;   // 4h * 2048 ushort

// ---------------------------------------------------------------------------
// Build kernel: fragment-ordered per-head images of A+D, C, B-D (f32), W2 (bf16).
// Slot (f, l): f = kk*4+mt; k = 16*mt+(l&15); d0 = 32*kk+8*(l>>4); 8 d values.
// ---------------------------------------------------------------------------
__global__ __launch_bounds__(256) void build_kernel(
    const float* __restrict__ W1, const float* __restrict__ W2,
    float* __restrict__ sad, float* __restrict__ sc, float* __restrict__ sbd,
    ushort* __restrict__ w2i)
{
    const int h = blockIdx.x;
    const int t = threadIdx.x;
    const float* w1h = W1 + (size_t)h * F * H1;

    #pragma unroll
    for (int half = 0; half < 2; ++half) {
        const int sl = half * 256 + t;          // 0..511
        const int f  = sl >> 6, l = sl & 63;
        const int mt = f & 3, kk = f >> 2;
        const int k  = 16 * mt + (l & 15);
        const int d0 = 32 * kk + ((l >> 4) << 3);
        float vs[8], vc[8], vb[8];
        #pragma unroll
        for (int j = 0; j < 8; ++j) {
            const int d = d0 + j;
            float A  = w1h[d * 64 + k];
            float Bv = w1h[(64 + d) * 64 + k];
            float C  = w1h[(128 + d) * 64 + k];
            float Dv = w1h[(192 + d) * 64 + k];
            vs[j] = A + Dv; vc[j] = C; vb[j] = Bv - Dv;
        }
        const size_t off = ((size_t)h * 512 + sl) * 8;
        *(f32x4*)&sad[off]     = *(f32x4*)&vs[0];
        *(f32x4*)&sad[off + 4] = *(f32x4*)&vs[4];
        *(f32x4*)&sc [off]     = *(f32x4*)&vc[0];
        *(f32x4*)&sc [off + 4] = *(f32x4*)&vc[4];
        *(f32x4*)&sbd[off]     = *(f32x4*)&vb[0];
        *(f32x4*)&sbd[off + 4] = *(f32x4*)&vb[4];
    }

    {   // W2 fragment image: f2 = w*2+mt2; m = 16*mt2+(l&15); k20 = 32*w+8*(l>>4)
        const int f2 = t >> 6, l = t & 63;
        const int mt2 = f2 & 1, w = f2 >> 1;
        const int m = 16 * mt2 + (l & 15), k20 = 32 * w + ((l >> 4) << 3);
        const float* w2h = W2 + (size_t)h * H1 * H2;
        uint4v u = { cvtpk(w2h[(k20 + 0) * 32 + m], w2h[(k20 + 1) * 32 + m]),
                     cvtpk(w2h[(k20 + 2) * 32 + m], w2h[(k20 + 3) * 32 + m]),
                     cvtpk(w2h[(k20 + 4) * 32 + m], w2h[(k20 + 5) * 32 + m]),
                     cvtpk(w2h[(k20 + 6) * 32 + m], w2h[(k20 + 7) * 32 + m]) };
        *(uint4v*)&w2i[((size_t)h * 4 + f2) * 512 + l * 8] = u;
    }
}

// ---------------------------------------------------------------------------
// One block per batch row b; 4 waves; wave = head, end-to-end. 38 KB LDS ->
// 4 blocks/CU. Scores in registers (full unroll); weights/head-out/proj
// partials overlay the dead relay region; projection fused at the end.
// ---------------------------------------------------------------------------
__global__ __launch_bounds__(256, 4) void fused_b_kernel(
    const float* __restrict__ query, const float* __restrict__ keys,
    const int* __restrict__ mask,
    const float* __restrict__ sad, const float* __restrict__ sc,
    const float* __restrict__ sbd, const ushort* __restrict__ w2i,
    const float* __restrict__ b1, const float* __restrict__ a1,
    const float* __restrict__ b2, const float* __restrict__ a2,
    const float* __restrict__ W3, const float* __restrict__ b3,
    const float* __restrict__ Wo, const float* __restrict__ bo,
    float* __restrict__ out)
{
    __shared__ ushort sK[200 * PK];        // keys bf16 [s][d] (no pad rows)
    __shared__ ushort relay[4][16 * PK];   // per-wave: relay; post-loop overlay:
                                           //   f32 [0..200) weights, [200..264) head-out, [264..328) proj partial

    const int b    = blockIdx.x;
    const int t    = threadIdx.x;
    const int lane = t & 63;
    const int h    = t >> 6;               // wave = head
    const int g    = lane >> 4;
    const int ln16 = lane & 15;

    // ---- mask: 4 coalesced loads -> 13-bit register mask in (st, ln16) layout ----
    unsigned mbits = 0;
    {
        int mval[4];
        #pragma unroll
        for (int c = 0; c < 4; ++c) {
            int s = lane + 64 * c;
            mval[c] = (s < S) ? mask[(size_t)b * S + s] : 0;
        }
        #pragma unroll
        for (int st = 0; st < 13; ++st) {
            const int src = 16 * (st & 3) + ln16;
            int v = (st >> 2) == 0 ? __shfl(mval[0], src)
                  : (st >> 2) == 1 ? __shfl(mval[1], src)
                  : (st >> 2) == 2 ? __shfl(mval[2], src)
                  :                  __shfl(mval[3], src);
            mbits |= (v != 0) ? (1u << st) : 0u;
        }
    }

    // ---- cooperative keys staging (bf16) ----
    {
        const float4* k4 = (const float4*)(keys + (size_t)b * S * D);
        for (int idx = t; idx < S * D / 4; idx += 256) {
            float4 v = k4[idx];
            int s = idx >> 4, dc = (idx & 15) * 4;
            *(uint2*)&sK[s * PK + dc] = make_uint2(cvtpk(v.x, v.y), cvtpk(v.z, v.w));
        }
    }

    // ---- register Weff build from fragment images + q ----
    const float* qb = query + (size_t)b * D;
    bf16x8 wh[4][2];
    float qtp0 = 0.f, qtp1 = 0.f, qtp2 = 0.f, qtp3 = 0.f;
    #pragma unroll
    for (int kk = 0; kk < 2; ++kk) {
        const int d0 = 32 * kk + 8 * g;
        f32x4 q0 = *(const f32x4*)&qb[d0];
        f32x4 q1 = *(const f32x4*)&qb[d0 + 4];
        #pragma unroll
        for (int mt = 0; mt < 4; ++mt) {
            const int f = kk * 4 + mt;
            const size_t off = ((size_t)h * 512 + f * 64 + lane) * 8;
            f32x4 s0 = *(const f32x4*)&sad[off], s1 = *(const f32x4*)&sad[off + 4];
            f32x4 c0 = *(const f32x4*)&sc [off], c1 = *(const f32x4*)&sc [off + 4];
            f32x4 bd0 = *(const f32x4*)&sbd[off], bd1 = *(const f32x4*)&sbd[off + 4];
            float w0 = s0[0] + q0[0] * c0[0], w1 = s0[1] + q0[1] * c0[1];
            float w2 = s0[2] + q0[2] * c0[2], w3 = s0[3] + q0[3] * c0[3];
            float w4 = s1[0] + q1[0] * c1[0], w5 = s1[1] + q1[1] * c1[1];
            float w6 = s1[2] + q1[2] * c1[2], w7 = s1[3] + q1[3] * c1[3];
            uint4v u = { cvtpk(w0, w1), cvtpk(w2, w3), cvtpk(w4, w5), cvtpk(w6, w7) };
            wh[mt][kk] = __builtin_bit_cast(bf16x8, u);
            float d = q0[0]*bd0[0] + q0[1]*bd0[1] + q0[2]*bd0[2] + q0[3]*bd0[3]
                    + q1[0]*bd1[0] + q1[1]*bd1[1] + q1[2]*bd1[2] + q1[3]*bd1[3];
            if (mt == 0) qtp0 += d; else if (mt == 1) qtp1 += d;
            else if (mt == 2) qtp2 += d; else qtp3 += d;
        }
    }
    qtp0 += __shfl_xor(qtp0, 16); qtp0 += __shfl_xor(qtp0, 32);
    qtp1 += __shfl_xor(qtp1, 16); qtp1 += __shfl_xor(qtp1, 32);
    qtp2 += __shfl_xor(qtp2, 16); qtp2 += __shfl_xor(qtp2, 32);
    qtp3 += __shfl_xor(qtp3, 16); qtp3 += __shfl_xor(qtp3, 32);
    f32x4 qtv[4];
    #pragma unroll
    for (int mt = 0; mt < 4; ++mt) {
        float src = (mt == 0) ? qtp0 : (mt == 1) ? qtp1 : (mt == 2) ? qtp2 : qtp3;
        f32x4 b1v = *(const f32x4*)&b1[h * 64 + mt * 16 + 4 * g];
        f32x4 v;
        #pragma unroll
        for (int i = 0; i < 4; ++i) v[i] = __shfl(src, 4 * g + i) + b1v[i];
        qtv[mt] = v;
    }

    // ---- W2 fragments + constants ----
    bf16x8 w2f[2][2];
    #pragma unroll
    for (int w = 0; w < 2; ++w)
        #pragma unroll
        for (int mt2 = 0; mt2 < 2; ++mt2)
            w2f[w][mt2] = *(const bf16x8*)&w2i[((size_t)h * 4 + w * 2 + mt2) * 512 + lane * 8];
    f32x4 b2v[2], w3v[2];
    #pragma unroll
    for (int mt2 = 0; mt2 < 2; ++mt2) {
        b2v[mt2] = *(const f32x4*)&b2[h * 32 + mt2 * 16 + 4 * g];
        w3v[mt2] = *(const f32x4*)&W3[h * 32 + mt2 * 16 + 4 * g];
    }
    const float a1v = a1[h], a2v = a2[h], b3v = b3[h];

    __syncthreads();   // barrier 1: sK ready

    ushort* myR = relay[h];
    float sc13[13];

    // ---- main loop: 13 s-tiles, fully unrolled, scores stay in registers ----
    #pragma unroll
    for (int st = 0; st < 13; ++st) {
        int srow = st * 16 + ln16;
        srow = srow > 199 ? 199 : srow;
        bf16x8 bk0 = *(const bf16x8*)&sK[srow * PK + 0  + 8 * g];
        bf16x8 bk1 = *(const bf16x8*)&sK[srow * PK + 32 + 8 * g];

        f32x4 acc[4] = { qtv[0], qtv[1], qtv[2], qtv[3] };
        #pragma unroll
        for (int mt = 0; mt < 4; ++mt)
            acc[mt] = __builtin_amdgcn_mfma_f32_16x16x32_bf16(wh[mt][0], bk0, acc[mt], 0, 0, 0);
        #pragma unroll
        for (int mt = 0; mt < 4; ++mt)
            acc[mt] = __builtin_amdgcn_mfma_f32_16x16x32_bf16(wh[mt][1], bk1, acc[mt], 0, 0, 0);

        #pragma unroll
        for (int mt = 0; mt < 4; ++mt) {
            float v0 = acc[mt][0]; v0 = v0 > 0.f ? v0 : a1v * v0;
            float v1 = acc[mt][1]; v1 = v1 > 0.f ? v1 : a1v * v1;
            float v2 = acc[mt][2]; v2 = v2 > 0.f ? v2 : a1v * v2;
            float v3 = acc[mt][3]; v3 = v3 > 0.f ? v3 : a1v * v3;
            *(uint2*)&myR[ln16 * PK + mt * 16 + 4 * g] =
                make_uint2(cvtpk(v0, v1), cvtpk(v2, v3));
        }

        f32x4 acc2[2] = { b2v[0], b2v[1] };
        #pragma unroll
        for (int w = 0; w < 2; ++w) {
            bf16x8 Bh = *(const bf16x8*)&myR[ln16 * PK + w * 32 + 8 * g];
            #pragma unroll
            for (int mt2 = 0; mt2 < 2; ++mt2)
                acc2[mt2] = __builtin_amdgcn_mfma_f32_16x16x32_bf16(w2f[w][mt2], Bh, acc2[mt2], 0, 0, 0);
        }

        float part = 0.f;
        #pragma unroll
        for (int mt2 = 0; mt2 < 2; ++mt2) {
            #pragma unroll
            for (int i = 0; i < 4; ++i) {
                float v = acc2[mt2][i];
                v = v > 0.f ? v : a2v * v;
                part += v * w3v[mt2][i];
            }
        }
        part += __shfl_xor(part, 16);
        part += __shfl_xor(part, 32);
        sc13[st] = part + b3v;   // every lane holds score[16*st + ln16]
    }

    // ---- softmax in registers (reduce across the 16 ln16 lanes) ----
    float* ws = (float*)myR;    // relay region now dead for this wave
    {
        float M = -INFINITY;
        #pragma unroll
        for (int st = 0; st < 13; ++st)
            if ((mbits >> st) & 1) M = fmaxf(M, sc13[st]);
        #pragma unroll
        for (int off = 1; off < 16; off <<= 1) M = fmaxf(M, __shfl_xor(M, off));
        float Z = 0.f, e[13];
        #pragma unroll
        for (int st = 0; st < 13; ++st) {
            e[st] = ((mbits >> st) & 1) ? __expf(sc13[st] - M) : 0.f;
            Z += e[st];
        }
        #pragma unroll
        for (int off = 1; off < 16; off <<= 1) Z += __shfl_xor(Z, off);
        const float inv = Z > 0.f ? 1.f / Z : 0.f;
        if (g == 0) {
            #pragma unroll
            for (int st = 0; st < 13; ++st) {
                const int s = st * 16 + ln16;
                if (st < 12 || ln16 < 8) ws[s] = e[st] * inv;
            }
        }
    }

    // ---- attend from LDS bf16 keys (weights broadcast from own slot) ----
    {
        const int sg = lane >> 4, dq = ln16;
        float ax = 0.f, ay = 0.f, az = 0.f, aw = 0.f;
        #pragma unroll 5
        for (int i = 0; i < 50; ++i) {
            const int s = sg * 50 + i;
            const float w = ws[s];
            uint2 kv = *(const uint2*)&sK[s * PK + 4 * dq];
            ax += w * lo16f(kv.x); ay += w * hi16f(kv.x);
            az += w * lo16f(kv.y); aw += w * hi16f(kv.y);
        }
        ax += __shfl_xor(ax, 16); ay += __shfl_xor(ay, 16);
        az += __shfl_xor(az, 16); aw += __shfl_xor(aw, 16);
        ax += __shfl_xor(ax, 32); ay += __shfl_xor(ay, 32);
        az += __shfl_xor(az, 32); aw += __shfl_xor(aw, 32);
        if (lane < 16) {
            float4 o = { ax, ay, az, aw };
            *(float4*)&ws[200 + 4 * dq] = o;   // head-out in own slot
        }
    }
    __syncthreads();   // barrier 2: all head-outs visible

    // ---- fused projection: wave h covers d in [16h, 16h+16) ----
    {
        float p = 0.f;
        #pragma unroll
        for (int j = 0; j < 16; ++j) {
            const int d = 16 * h + j;
            const float cmb = 0.25f * (((const float*)relay[0])[200 + d]
                                     + ((const float*)relay[1])[200 + d]
                                     + ((const float*)relay[2])[200 + d]
                                     + ((const float*)relay[3])[200 + d]);
            p += cmb * Wo[d * 64 + lane];
        }
        ws[264 + lane] = p;
    }
    __syncthreads();   // barrier 3: proj partials visible
    if (t < 64) {
        float o = bo[t] + ((const float*)relay[0])[264 + t]
                        + ((const float*)relay[1])[264 + t]
                        + ((const float*)relay[2])[264 + t]
                        + ((const float*)relay[3])[264 + t];
        out[(size_t)b * D + t] = o;
    }
}

// ---------------------------------------------------------------------------
extern "C" void kernel_launch(void* const* d_in, const int* in_sizes, int n_in,
                              void* d_out, int out_size, void* d_ws, size_t ws_size,
                              hipStream_t stream) {
    const float* query = (const float*)d_in[0];
    const float* keys  = (const float*)d_in[1];
    const int*   mask  = (const int*)d_in[2];
    const float* W1 = (const float*)d_in[3];
    const float* b1 = (const float*)d_in[4];
    const float* a1 = (const float*)d_in[5];
    const float* W2 = (const float*)d_in[6];
    const float* b2 = (const float*)d_in[7];
    const float* a2 = (const float*)d_in[8];
    const float* W3 = (const float*)d_in[9];
    const float* b3 = (const float*)d_in[10];
    const float* Wo = (const float*)d_in[11];
    const float* bo = (const float*)d_in[12];

    float* out  = (float*)d_out;
    char*  ws   = (char*)d_ws;
    float* sad  = (float*)(ws + SAD_OFF);
    float* sc   = (float*)(ws + SC_OFF);
    float* sbd  = (float*)(ws + SBD_OFF);
    ushort* w2i = (ushort*)(ws + W2I_OFF);

    build_kernel<<<dim3(H), 256, 0, stream>>>(W1, W2, sad, sc, sbd, w2i);
    fused_b_kernel<<<dim3(B), 256, 0, stream>>>(
        query, keys, mask, sad, sc, sbd, w2i, b1, a1, b2, a2, W3, b3,
        Wo, bo, out);
}

// Round 14
// 64.631 us; speedup vs baseline: 1.9324x; 1.0253x over previous
//
#include <hip/hip_runtime.h>
#include <math.h>

constexpr int B  = 2048;
constexpr int S  = 200;
constexpr int D  = 64;
constexpr int H  = 4;
constexpr int H1 = 64;
constexpr int H2 = 32;
constexpr int F  = 256;

constexpr int PK = 72;   // ushort pitch: 144 B rows (16B multiple), ~2-way banks

typedef short bf16x8 __attribute__((ext_vector_type(8)));
typedef float f32x4  __attribute__((ext_vector_type(4)));
typedef unsigned uint4v __attribute__((ext_vector_type(4)));

__device__ __forceinline__ unsigned cvtpk(float a, float b) {
    unsigned r;
    asm volatile("v_cvt_pk_bf16_f32 %0, %1, %2" : "=v"(r) : "v"(a), "v"(b));
    return r;
}
__device__ __forceinline__ float lo16f(unsigned w) { return __builtin_bit_cast(float, w << 16); }
__device__ __forceinline__ float hi16f(unsigned w) { return __builtin_bit_cast(float, w & 0xffff0000u); }

// ---- workspace layout (per-head constant images only, ~208 KB, L2-resident) ----
constexpr size_t SAD_OFF = 0;                        // 4h * 4096 f32
constexpr size_t SC_OFF  = SAD_OFF + 4 * 4096 * 4;
constexpr size_t SBD_OFF = SC_OFF  + 4 * 4096 * 4;
constexpr size_t W2I_OFF = SBD_OFF + 4 * 4096 * 4;   // 4h * 2048 ushort

// ---------------------------------------------------------------------------
// Build kernel: fragment-ordered per-head images of A+D, C, B-D (f32), W2 (bf16).
// Slot (f, l): f = kk*4+mt; k = 16*mt+(l&15); d0 = 32*kk+8*(l>>4); 8 d values.
// ---------------------------------------------------------------------------
__global__ __launch_bounds__(256) void build_kernel(
    const float* __restrict__ W1, const float* __restrict__ W2,
    float* __restrict__ sad, float* __restrict__ sc, float* __restrict__ sbd,
    ushort* __restrict__ w2i)
{
    const int h = blockIdx.x;
    const int t = threadIdx.x;
    const float* w1h = W1 + (size_t)h * F * H1;

    #pragma unroll
    for (int half = 0; half < 2; ++half) {
        const int sl = half * 256 + t;          // 0..511
        const int f  = sl >> 6, l = sl & 63;
        const int mt = f & 3, kk = f >> 2;
        const int k  = 16 * mt + (l & 15);
        const int d0 = 32 * kk + ((l >> 4) << 3);
        float vs[8], vc[8], vb[8];
        #pragma unroll
        for (int j = 0; j < 8; ++j) {
            const int d = d0 + j;
            float A  = w1h[d * 64 + k];
            float Bv = w1h[(64 + d) * 64 + k];
            float C  = w1h[(128 + d) * 64 + k];
            float Dv = w1h[(192 + d) * 64 + k];
            vs[j] = A + Dv; vc[j] = C; vb[j] = Bv - Dv;
        }
        const size_t off = ((size_t)h * 512 + sl) * 8;
        *(f32x4*)&sad[off]     = *(f32x4*)&vs[0];
        *(f32x4*)&sad[off + 4] = *(f32x4*)&vs[4];
        *(f32x4*)&sc [off]     = *(f32x4*)&vc[0];
        *(f32x4*)&sc [off + 4] = *(f32x4*)&vc[4];
        *(f32x4*)&sbd[off]     = *(f32x4*)&vb[0];
        *(f32x4*)&sbd[off + 4] = *(f32x4*)&vb[4];
    }

    {   // W2 fragment image: f2 = w*2+mt2; m = 16*mt2+(l&15); k20 = 32*w+8*(l>>4)
        const int f2 = t >> 6, l = t & 63;
        const int mt2 = f2 & 1, w = f2 >> 1;
        const int m = 16 * mt2 + (l & 15), k20 = 32 * w + ((l >> 4) << 3);
        const float* w2h = W2 + (size_t)h * H1 * H2;
        uint4v u = { cvtpk(w2h[(k20 + 0) * 32 + m], w2h[(k20 + 1) * 32 + m]),
                     cvtpk(w2h[(k20 + 2) * 32 + m], w2h[(k20 + 3) * 32 + m]),
                     cvtpk(w2h[(k20 + 4) * 32 + m], w2h[(k20 + 5) * 32 + m]),
                     cvtpk(w2h[(k20 + 6) * 32 + m], w2h[(k20 + 7) * 32 + m]) };
        *(uint4v*)&w2i[((size_t)h * 4 + f2) * 512 + l * 8] = u;
    }
}

// ---------------------------------------------------------------------------
// One block per batch row b; 4 waves; wave = head, end-to-end. 38 KB LDS;
// bound (256,3) so the allocator is NOT starved (round-13 (256,4) spilled).
// Scores in registers; two-pass softmax (no e[] array); projection fused.
// ---------------------------------------------------------------------------
__global__ __launch_bounds__(256, 3) void fused_b_kernel(
    const float* __restrict__ query, const float* __restrict__ keys,
    const int* __restrict__ mask,
    const float* __restrict__ sad, const float* __restrict__ sc,
    const float* __restrict__ sbd, const ushort* __restrict__ w2i,
    const float* __restrict__ b1, const float* __restrict__ a1,
    const float* __restrict__ b2, const float* __restrict__ a2,
    const float* __restrict__ W3, const float* __restrict__ b3,
    const float* __restrict__ Wo, const float* __restrict__ bo,
    float* __restrict__ out)
{
    __shared__ ushort sK[200 * PK];        // keys bf16 [s][d]
    __shared__ ushort relay[4][16 * PK];   // per-wave: relay; post-loop overlay:
                                           //   f32 [0..200) weights, [200..264) head-out, [264..328) proj partial

    const int b    = blockIdx.x;
    const int t    = threadIdx.x;
    const int lane = t & 63;
    const int h    = t >> 6;               // wave = head
    const int g    = lane >> 4;
    const int ln16 = lane & 15;

    // ---- mask: 4 coalesced loads -> 13-bit register mask in (st, ln16) layout ----
    unsigned mbits = 0;
    {
        int mval[4];
        #pragma unroll
        for (int c = 0; c < 4; ++c) {
            int s = lane + 64 * c;
            mval[c] = (s < S) ? mask[(size_t)b * S + s] : 0;
        }
        #pragma unroll
        for (int st = 0; st < 13; ++st) {
            const int src = 16 * (st & 3) + ln16;
            int v = (st >> 2) == 0 ? __shfl(mval[0], src)
                  : (st >> 2) == 1 ? __shfl(mval[1], src)
                  : (st >> 2) == 2 ? __shfl(mval[2], src)
                  :                  __shfl(mval[3], src);
            mbits |= (v != 0) ? (1u << st) : 0u;
        }
    }

    // ---- cooperative keys staging (bf16) ----
    {
        const float4* k4 = (const float4*)(keys + (size_t)b * S * D);
        for (int idx = t; idx < S * D / 4; idx += 256) {
            float4 v = k4[idx];
            int s = idx >> 4, dc = (idx & 15) * 4;
            *(uint2*)&sK[s * PK + dc] = make_uint2(cvtpk(v.x, v.y), cvtpk(v.z, v.w));
        }
    }

    // ---- register Weff build from fragment images + q ----
    const float* qb = query + (size_t)b * D;
    bf16x8 wh[4][2];
    float qtp0 = 0.f, qtp1 = 0.f, qtp2 = 0.f, qtp3 = 0.f;
    #pragma unroll
    for (int kk = 0; kk < 2; ++kk) {
        const int d0 = 32 * kk + 8 * g;
        f32x4 q0 = *(const f32x4*)&qb[d0];
        f32x4 q1 = *(const f32x4*)&qb[d0 + 4];
        #pragma unroll
        for (int mt = 0; mt < 4; ++mt) {
            const int f = kk * 4 + mt;
            const size_t off = ((size_t)h * 512 + f * 64 + lane) * 8;
            f32x4 s0 = *(const f32x4*)&sad[off], s1 = *(const f32x4*)&sad[off + 4];
            f32x4 c0 = *(const f32x4*)&sc [off], c1 = *(const f32x4*)&sc [off + 4];
            f32x4 bd0 = *(const f32x4*)&sbd[off], bd1 = *(const f32x4*)&sbd[off + 4];
            float w0 = s0[0] + q0[0] * c0[0], w1 = s0[1] + q0[1] * c0[1];
            float w2 = s0[2] + q0[2] * c0[2], w3 = s0[3] + q0[3] * c0[3];
            float w4 = s1[0] + q1[0] * c1[0], w5 = s1[1] + q1[1] * c1[1];
            float w6 = s1[2] + q1[2] * c1[2], w7 = s1[3] + q1[3] * c1[3];
            uint4v u = { cvtpk(w0, w1), cvtpk(w2, w3), cvtpk(w4, w5), cvtpk(w6, w7) };
            wh[mt][kk] = __builtin_bit_cast(bf16x8, u);
            float d = q0[0]*bd0[0] + q0[1]*bd0[1] + q0[2]*bd0[2] + q0[3]*bd0[3]
                    + q1[0]*bd1[0] + q1[1]*bd1[1] + q1[2]*bd1[2] + q1[3]*bd1[3];
            if (mt == 0) qtp0 += d; else if (mt == 1) qtp1 += d;
            else if (mt == 2) qtp2 += d; else qtp3 += d;
        }
    }
    qtp0 += __shfl_xor(qtp0, 16); qtp0 += __shfl_xor(qtp0, 32);
    qtp1 += __shfl_xor(qtp1, 16); qtp1 += __shfl_xor(qtp1, 32);
    qtp2 += __shfl_xor(qtp2, 16); qtp2 += __shfl_xor(qtp2, 32);
    qtp3 += __shfl_xor(qtp3, 16); qtp3 += __shfl_xor(qtp3, 32);
    f32x4 qtv[4];
    #pragma unroll
    for (int mt = 0; mt < 4; ++mt) {
        float src = (mt == 0) ? qtp0 : (mt == 1) ? qtp1 : (mt == 2) ? qtp2 : qtp3;
        f32x4 b1v = *(const f32x4*)&b1[h * 64 + mt * 16 + 4 * g];
        f32x4 v;
        #pragma unroll
        for (int i = 0; i < 4; ++i) v[i] = __shfl(src, 4 * g + i) + b1v[i];
        qtv[mt] = v;
    }

    // ---- W2 fragments + constants ----
    bf16x8 w2f[2][2];
    #pragma unroll
    for (int w = 0; w < 2; ++w)
        #pragma unroll
        for (int mt2 = 0; mt2 < 2; ++mt2)
            w2f[w][mt2] = *(const bf16x8*)&w2i[((size_t)h * 4 + w * 2 + mt2) * 512 + lane * 8];
    f32x4 b2v[2], w3v[2];
    #pragma unroll
    for (int mt2 = 0; mt2 < 2; ++mt2) {
        b2v[mt2] = *(const f32x4*)&b2[h * 32 + mt2 * 16 + 4 * g];
        w3v[mt2] = *(const f32x4*)&W3[h * 32 + mt2 * 16 + 4 * g];
    }
    const float a1v = a1[h], a2v = a2[h], b3v = b3[h];

    __syncthreads();   // barrier 1: sK ready

    ushort* myR = relay[h];
    float sc13[13];

    // ---- main loop: 13 s-tiles, fully unrolled, scores stay in registers ----
    #pragma unroll
    for (int st = 0; st < 13; ++st) {
        int srow = st * 16 + ln16;
        srow = srow > 199 ? 199 : srow;
        bf16x8 bk0 = *(const bf16x8*)&sK[srow * PK + 0  + 8 * g];
        bf16x8 bk1 = *(const bf16x8*)&sK[srow * PK + 32 + 8 * g];

        f32x4 acc[4] = { qtv[0], qtv[1], qtv[2], qtv[3] };
        #pragma unroll
        for (int mt = 0; mt < 4; ++mt)
            acc[mt] = __builtin_amdgcn_mfma_f32_16x16x32_bf16(wh[mt][0], bk0, acc[mt], 0, 0, 0);
        #pragma unroll
        for (int mt = 0; mt < 4; ++mt)
            acc[mt] = __builtin_amdgcn_mfma_f32_16x16x32_bf16(wh[mt][1], bk1, acc[mt], 0, 0, 0);

        #pragma unroll
        for (int mt = 0; mt < 4; ++mt) {
            float v0 = acc[mt][0]; v0 = v0 > 0.f ? v0 : a1v * v0;
            float v1 = acc[mt][1]; v1 = v1 > 0.f ? v1 : a1v * v1;
            float v2 = acc[mt][2]; v2 = v2 > 0.f ? v2 : a1v * v2;
            float v3 = acc[mt][3]; v3 = v3 > 0.f ? v3 : a1v * v3;
            *(uint2*)&myR[ln16 * PK + mt * 16 + 4 * g] =
                make_uint2(cvtpk(v0, v1), cvtpk(v2, v3));
        }

        f32x4 acc2[2] = { b2v[0], b2v[1] };
        #pragma unroll
        for (int w = 0; w < 2; ++w) {
            bf16x8 Bh = *(const bf16x8*)&myR[ln16 * PK + w * 32 + 8 * g];
            #pragma unroll
            for (int mt2 = 0; mt2 < 2; ++mt2)
                acc2[mt2] = __builtin_amdgcn_mfma_f32_16x16x32_bf16(w2f[w][mt2], Bh, acc2[mt2], 0, 0, 0);
        }

        float part = 0.f;
        #pragma unroll
        for (int mt2 = 0; mt2 < 2; ++mt2) {
            #pragma unroll
            for (int i = 0; i < 4; ++i) {
                float v = acc2[mt2][i];
                v = v > 0.f ? v : a2v * v;
                part += v * w3v[mt2][i];
            }
        }
        part += __shfl_xor(part, 16);
        part += __shfl_xor(part, 32);
        sc13[st] = part + b3v;   // every lane holds score[16*st + ln16]
    }

    // ---- two-pass softmax in registers (no e[] array; exp recomputed) ----
    float* ws = (float*)myR;    // relay region now dead for this wave
    {
        float M = -INFINITY;
        #pragma unroll
        for (int st = 0; st < 13; ++st)
            if ((mbits >> st) & 1) M = fmaxf(M, sc13[st]);
        #pragma unroll
        for (int off = 1; off < 16; off <<= 1) M = fmaxf(M, __shfl_xor(M, off));
        float Z = 0.f;
        #pragma unroll
        for (int st = 0; st < 13; ++st)
            Z += ((mbits >> st) & 1) ? __expf(sc13[st] - M) : 0.f;
        #pragma unroll
        for (int off = 1; off < 16; off <<= 1) Z += __shfl_xor(Z, off);
        const float inv = Z > 0.f ? 1.f / Z : 0.f;
        if (g == 0) {
            #pragma unroll
            for (int st = 0; st < 13; ++st) {
                const int s = st * 16 + ln16;
                if (st < 12 || ln16 < 8)
                    ws[s] = ((mbits >> st) & 1) ? __expf(sc13[st] - M) * inv : 0.f;
            }
        }
    }

    // ---- attend from LDS bf16 keys (weights broadcast from own slot) ----
    {
        const int sg = lane >> 4, dq = ln16;
        float ax = 0.f, ay = 0.f, az = 0.f, aw = 0.f;
        #pragma unroll 5
        for (int i = 0; i < 50; ++i) {
            const int s = sg * 50 + i;
            const float w = ws[s];
            uint2 kv = *(const uint2*)&sK[s * PK + 4 * dq];
            ax += w * lo16f(kv.x); ay += w * hi16f(kv.x);
            az += w * lo16f(kv.y); aw += w * hi16f(kv.y);
        }
        ax += __shfl_xor(ax, 16); ay += __shfl_xor(ay, 16);
        az += __shfl_xor(az, 16); aw += __shfl_xor(aw, 16);
        ax += __shfl_xor(ax, 32); ay += __shfl_xor(ay, 32);
        az += __shfl_xor(az, 32); aw += __shfl_xor(aw, 32);
        if (lane < 16) {
            float4 o = { ax, ay, az, aw };
            *(float4*)&ws[200 + 4 * dq] = o;   // head-out in own slot
        }
    }
    __syncthreads();   // barrier 2: all head-outs visible

    // ---- fused projection: wave h covers d in [16h, 16h+16) ----
    {
        float p = 0.f;
        #pragma unroll
        for (int j = 0; j < 16; ++j) {
            const int d = 16 * h + j;
            const float cmb = 0.25f * (((const float*)relay[0])[200 + d]
                                     + ((const float*)relay[1])[200 + d]
                                     + ((const float*)relay[2])[200 + d]
                                     + ((const float*)relay[3])[200 + d]);
            p += cmb * Wo[d * 64 + lane];
        }
        ws[264 + lane] = p;
    }
    __syncthreads();   // barrier 3: proj partials visible
    if (t < 64) {
        float o = bo[t] + ((const float*)relay[0])[264 + t]
                        + ((const float*)relay[1])[264 + t]
                        + ((const float*)relay[2])[264 + t]
                        + ((const float*)relay[3])[264 + t];
        out[(size_t)b * D + t] = o;
    }
}

// ---------------------------------------------------------------------------
extern "C" void kernel_launch(void* const* d_in, const int* in_sizes, int n_in,
                              void* d_out, int out_size, void* d_ws, size_t ws_size,
                              hipStream_t stream) {
    const float* query = (const float*)d_in[0];
    const float* keys  = (const float*)d_in[1];
    const int*   mask  = (const int*)d_in[2];
    const float* W1 = (const float*)d_in[3];
    const float* b1 = (const float*)d_in[4];
    const float* a1 = (const float*)d_in[5];
    const float* W2 = (const float*)d_in[6];
    const float* b2 = (const float*)d_in[7];
    const float* a2 = (const float*)d_in[8];
    const float* W3 = (const float*)d_in[9];
    const float* b3 = (const float*)d_in[10];
    const float* Wo = (const float*)d_in[11];
    const float* bo = (const float*)d_in[12];

    float* out  = (float*)d_out;
    char*  ws   = (char*)d_ws;
    float* sad  = (float*)(ws + SAD_OFF);
    float* sc   = (float*)(ws + SC_OFF);
    float* sbd  = (float*)(ws + SBD_OFF);
    ushort* w2i = (ushort*)(ws + W2I_OFF);

    build_kernel<<<dim3(H), 256, 0, stream>>>(W1, W2, sad, sc, sbd, w2i);
    fused_b_kernel<<<dim3(B), 256, 0, stream>>>(
        query, keys, mask, sad, sc, sbd, w2i, b1, a1, b2, a2, W3, b3,
        Wo, bo, out);
}